// Round 2
// baseline (1277.734 us; speedup 1.0000x reference)
//
#include <hip/hip_runtime.h>
#include <hip/hip_bf16.h>

typedef __bf16 bf16;
typedef __bf16 bf16x8 __attribute__((ext_vector_type(8)));
typedef float f32x4 __attribute__((ext_vector_type(4)));

#define DEV static __device__ __forceinline__

#define BB 2
#define NTOK 512
#define NATOM 16384
#define CT 384
#define CA 128
#define CP 16
#define CS 384
#define NQ 32
#define NK 128
#define NH 4
#define DH 32
#define NWIN 512
#define MTOT (BB*NATOM) /* 32768 */
#define CSZ ((size_t)MTOT*CA)

// transposed-bf16 weight arena offsets (elements)
#define WT_COND_OFF 0        /* 18 x [128][128] */
#define WT_QKVG_OFF 294912   /* 12 x [128][128] */
#define WT_WO_OFF   491520   /* 3 x [128][128]  */
#define WT_T12_OFF  540672   /* 6 x [256][128]  */
#define WT_WTO_OFF  737280   /* 3 x [128][256]  */
#define WT_TOTAL    835584
#define BIAS_I      16777216 /* bias elems per block-i: 2*512*4096*4 */

DEV bf16x8 lds_ld8(const bf16* p){
  union { uint2 u[2]; bf16x8 v; } t;
  t.u[0] = *reinterpret_cast<const uint2*>(p);
  t.u[1] = *reinterpret_cast<const uint2*>(p + 4);
  return t.v;
}
DEV bf16x8 ldg8(const bf16* p){
  union { uint4 u; bf16x8 v; } t;
  t.u = *reinterpret_cast<const uint4*>(p);
  return t.v;
}
DEV f32x4 mfma16(bf16x8 a, bf16x8 b, f32x4 c){
  return __builtin_amdgcn_mfma_f32_16x16x32_bf16(a, b, c, 0, 0, 0);
}
DEV float sigmoidf_(float x){ return 1.f/(1.f + __expf(-x)); }
DEV float red_sum64(float v){
  #pragma unroll
  for (int off = 1; off < 64; off <<= 1) v += __shfl_xor(v, off);
  return v;
}

// ---------------- weight prep: f32 [K][N] -> bf16 [N][K] ----------------
__global__ __launch_bounds__(256) void wconv(
    const float* ag, const float* ab, const float* sk,
    const float* tg, const float* tb, const float* tk,
    const float* wq, const float* wk, const float* wv, const float* wg,
    const float* wo, const float* wt1, const float* wt2, const float* wto,
    bf16* __restrict__ wt){
  __shared__ __align__(16) bf16 T[64][264];
  int s = blockIdx.x;
  int mat, nslab;
  if (s < 66){ mat = s >> 1; nslab = s & 1; }
  else if (s < 90){ mat = 33 + (s-66)/4; nslab = (s-66)&3; }
  else { mat = 39 + ((s-90)>>1); nslab = (s-90)&1; }
  const float* src; int K, N; size_t dst;
  if (mat < 18){ int i = mat/6, t = mat - i*6;
    const float* base = t==0?ag:t==1?ab:t==2?sk:t==3?tg:t==4?tb:tk;
    src = base + (size_t)i*CS*CA; K=128; N=128; dst = WT_COND_OFF + (size_t)mat*16384; }
  else if (mat < 30){ int q = mat-18; int i=q>>2, sx=q&3;
    const float* base = sx==0?wq:sx==1?wk:sx==2?wv:wg;
    src = base + (size_t)i*16384; K=128; N=128; dst = WT_QKVG_OFF + (size_t)q*16384; }
  else if (mat < 33){ src = wo + (size_t)(mat-30)*16384; K=128; N=128;
    dst = WT_WO_OFF + (size_t)(mat-30)*16384; }
  else if (mat < 39){ int q = mat-33; int i=q>>1, sx=q&1;
    src = (sx? wt2 : wt1) + (size_t)i*32768; K=128; N=256;
    dst = WT_T12_OFF + (size_t)q*32768; }
  else { src = wto + (size_t)(mat-39)*32768; K=256; N=128;
    dst = WT_WTO_OFF + (size_t)(mat-39)*32768; }
  int n0 = nslab*64;
  int tid = threadIdx.x;
  for (int c = tid; c < K*16; c += 256){
    int k = c >> 4, nq = c & 15;
    float4 v = *reinterpret_cast<const float4*>(src + (size_t)k*N + n0 + nq*4);
    T[nq*4+0][k] = (bf16)v.x; T[nq*4+1][k] = (bf16)v.y;
    T[nq*4+2][k] = (bf16)v.z; T[nq*4+3][k] = (bf16)v.w;
  }
  __syncthreads();
  int KQ = K >> 3;
  for (int c = tid; c < 64*KQ; c += 256){
    int n = c / KQ, kq = c - n*KQ;
    uint4 d = *reinterpret_cast<const uint4*>(&T[n][kq*8]);
    *reinterpret_cast<uint4*>(wt + dst + (size_t)(n0+n)*K + kq*8) = d;
  }
}

// ---------------- small prologue kernels ----------------
__global__ __launch_bounds__(128) void token_gemm(const float* __restrict__ a,
    const float* __restrict__ Wa, float* __restrict__ aW){
  __shared__ float arow[CT];
  int row = blockIdx.x;
  for (int j = threadIdx.x; j < CT; j += 128) arow[j] = a[(size_t)row*CT + j];
  __syncthreads();
  int c = threadIdx.x;
  float s = 0.f;
  for (int j = 0; j < CT; j++) s += arow[j] * Wa[(size_t)j*CA + c];
  aW[(size_t)row*CA + c] = s;
}

__global__ __launch_bounds__(256) void build_x0(const float* __restrict__ aW,
    const float* __restrict__ ef, const float* __restrict__ amask,
    const int* __restrict__ a2t, float* __restrict__ x,
    bf16* __restrict__ snc, float* __restrict__ tval){
  int ga = blockIdx.x * 4 + (threadIdx.x >> 6);
  int lane = threadIdx.x & 63;
  int b = ga >> 14;
  int tok = a2t[ga];
  float2 av = *reinterpret_cast<const float2*>(aW + ((size_t)(b*NTOK + tok))*CA + lane*2);
  float2 ev = *reinterpret_cast<const float2*>(ef + (size_t)ga*CA + lane*2);
  float m = amask[ga];
  *reinterpret_cast<float2*>(x + (size_t)ga*CA + lane*2) =
      make_float2((av.x + ev.x)*m, (av.y + ev.y)*m);
  float s = red_sum64(ev.x + ev.y);
  float mu = s * (1.f/384.f);
  float d0 = ev.x - mu, d1 = ev.y - mu;
  float vs = red_sum64(d0*d0 + d1*d1);
  float var = (vs + 256.f*mu*mu) * (1.f/384.f);
  float rs = rsqrtf(var + 1e-5f);
  bf16* sp = snc + (size_t)ga*CA + lane*2;
  sp[0] = (bf16)(d0*rs); sp[1] = (bf16)(d1*rs);
  if (lane == 0) tval[ga] = -mu*rs;
}

__global__ __launch_bounds__(128) void colsums(const float* ag, const float* ab,
    const float* sk, const float* tg, const float* tb, const float* tk,
    float* __restrict__ cs){
  int mat = blockIdx.x;              // 0..17 = i*6+t
  int i = mat / 6, t = mat % 6;
  const float* base = t==0?ag : t==1?ab : t==2?sk : t==3?tg : t==4?tb : tk;
  const float* W = base + (size_t)i*CS*CA;
  int c = threadIdx.x;
  float s = 0.f;
  for (int k = CA; k < CS; k++) s += W[(size_t)k*CA + c];
  cs[(size_t)mat*CA + c] = s;
}

// ---------------- all conditioning GEMMs, LDS-free ----------------
__global__ __launch_bounds__(256) void cond_all(const bf16* __restrict__ snc,
    const float* __restrict__ tval, const bf16* __restrict__ wtc,
    const float* __restrict__ ag_b, const float* __restrict__ sk_b,
    const float* __restrict__ tg_b, const float* __restrict__ tk_b,
    const float* __restrict__ cs, bf16* __restrict__ cond){
  int tid = threadIdx.x, wave = tid >> 6, lane = tid & 63;
  int l16 = lane & 15, quad = lane >> 4;
  int m0 = blockIdx.x*64; int i = blockIdx.y;
  const bf16* Ar = snc + (size_t)(m0 + wave*16 + l16)*CA;
  bf16x8 a[4];
  #pragma unroll
  for (int ks = 0; ks < 4; ks++) a[ks] = ldg8(Ar + ks*32 + quad*8);
  float tv[4];
  #pragma unroll
  for (int r = 0; r < 4; r++) tv[r] = tval[m0 + wave*16 + quad*4 + r];
  for (int t = 0; t < 6; t++){
    const bf16* Wt = wtc + (size_t)(i*6+t)*16384;
    const float* csr = cs + (size_t)(i*6+t)*CA;
    const float* bias = t==0 ? ag_b + (size_t)i*CA : t==2 ? sk_b + (size_t)i*CA
                      : t==3 ? tg_b + (size_t)i*CA : t==5 ? tk_b + (size_t)i*CA : nullptr;
    bool sig = (t==0)||(t==2)||(t==3)||(t==5);
    f32x4 z = {0.f,0.f,0.f,0.f};
    f32x4 acc[8];
    #pragma unroll
    for (int nt = 0; nt < 8; nt++) acc[nt] = z;
    #pragma unroll
    for (int nt = 0; nt < 8; nt++){
      const bf16* Bp = Wt + (size_t)(nt*16 + l16)*128 + quad*8;
      #pragma unroll
      for (int ks = 0; ks < 4; ks++)
        acc[nt] = mfma16(a[ks], ldg8(Bp + ks*32), acc[nt]);
    }
    bf16* op = cond + (size_t)(i*6+t)*CSZ;
    #pragma unroll
    for (int nt = 0; nt < 8; nt++)
    #pragma unroll
    for (int r = 0; r < 4; r++){
      int m = m0 + wave*16 + quad*4 + r;
      int n = nt*16 + l16;
      float v = acc[nt][r] + tv[r]*csr[n];
      if (bias) v += bias[n];
      if (sig)  v = sigmoidf_(v);
      op[(size_t)m*CA + n] = (bf16)v;
    }
  }
}

// ---------------- pair bias for all 3 blocks, one p_lm pass ----------------
__global__ __launch_bounds__(256) void bias_all(const float* __restrict__ p_lm,
    const float* __restrict__ pg, const float* __restrict__ pb,
    const float* __restrict__ wpb, bf16* __restrict__ biasg){
  __shared__ f32x4 wjS[3][16];
  __shared__ f32x4 extraS[3][2];
  int w = blockIdx.x, b = blockIdx.y;
  int tid = threadIdx.x;
  if (tid < 48){
    int i = tid >> 4, j = tid & 15;
    f32x4 wp = *reinterpret_cast<const f32x4*>(wpb + (size_t)(i*16+j)*4);
    wjS[i][j] = pg[i*16+j]*wp;
  }
  __syncthreads();
  if (tid < 3){
    f32x4 s = {0.f,0.f,0.f,0.f}, c = {0.f,0.f,0.f,0.f};
    for (int j = 0; j < 16; j++){
      s += wjS[tid][j];
      f32x4 wp = *reinterpret_cast<const f32x4*>(wpb + (size_t)(tid*16+j)*4);
      c += pb[tid*16+j]*wp;
    }
    extraS[tid][0] = s; extraS[tid][1] = c;
  }
  __syncthreads();
  size_t pbase = (size_t)(b*NWIN + w)*(NQ*NK*CP);
  size_t obase = (size_t)(b*NWIN + w)*4096*4;
  for (int i = 0; i < 3; i++){
    f32x4 wj[16];
    #pragma unroll
    for (int j = 0; j < 16; j++) wj[j] = wjS[i][j];
    f32x4 wsum = extraS[i][0], cc = extraS[i][1];
    bf16* ob = biasg + (size_t)i*BIAS_I + obase;
    #pragma unroll 2
    for (int t = 0; t < 16; t++){
      int pid = t*256 + tid;
      const float* pp = p_lm + pbase + (size_t)pid*16;
      float4 p0 = *reinterpret_cast<const float4*>(pp);
      float4 p1 = *reinterpret_cast<const float4*>(pp + 4);
      float4 p2 = *reinterpret_cast<const float4*>(pp + 8);
      float4 p3 = *reinterpret_cast<const float4*>(pp + 12);
      float sm = p0.x+p0.y+p0.z+p0.w + p1.x+p1.y+p1.z+p1.w
               + p2.x+p2.y+p2.z+p2.w + p3.x+p3.y+p3.z+p3.w;
      float sq = p0.x*p0.x+p0.y*p0.y+p0.z*p0.z+p0.w*p0.w
               + p1.x*p1.x+p1.y*p1.y+p1.z*p1.z+p1.w*p1.w
               + p2.x*p2.x+p2.y*p2.y+p2.z*p2.z+p2.w*p2.w
               + p3.x*p3.x+p3.y*p3.y+p3.z*p3.z+p3.w*p3.w;
      f32x4 dw = {0.f,0.f,0.f,0.f};
      dw += p0.x*wj[0];  dw += p0.y*wj[1];  dw += p0.z*wj[2];  dw += p0.w*wj[3];
      dw += p1.x*wj[4];  dw += p1.y*wj[5];  dw += p1.z*wj[6];  dw += p1.w*wj[7];
      dw += p2.x*wj[8];  dw += p2.y*wj[9];  dw += p2.z*wj[10]; dw += p2.w*wj[11];
      dw += p3.x*wj[12]; dw += p3.y*wj[13]; dw += p3.z*wj[14]; dw += p3.w*wj[15];
      float mu = sm * (1.f/16.f);
      float var = fmaxf(sq*(1.f/16.f) - mu*mu, 0.f);
      float rsg = rsqrtf(var + 1e-5f);
      f32x4 b4 = rsg*(dw - mu*wsum) + cc;
      union { uint2 u; bf16 hh[4]; } tb;
      tb.hh[0] = (bf16)b4.x; tb.hh[1] = (bf16)b4.y;
      tb.hh[2] = (bf16)b4.z; tb.hh[3] = (bf16)b4.w;
      *reinterpret_cast<uint2*>(ob + (size_t)pid*4) = tb.u;
    }
  }
}

// ---------------- AdaLN (standalone, used once for block 0) ----------------
__global__ __launch_bounds__(256) void adaln_kernel(const float* __restrict__ x,
    const bf16* __restrict__ g, const bf16* __restrict__ bt, bf16* __restrict__ outp){
  int ga = blockIdx.x * 4 + (threadIdx.x >> 6);
  int lane = threadIdx.x & 63;
  float2 xv = *reinterpret_cast<const float2*>(x + (size_t)ga*CA + lane*2);
  float s = red_sum64(xv.x + xv.y);
  float mu = s * (1.f/128.f);
  float d0 = xv.x - mu, d1 = xv.y - mu;
  float vs = red_sum64(d0*d0 + d1*d1);
  float rs = rsqrtf(vs*(1.f/128.f) + 1e-5f);
  const bf16* gp = g  + (size_t)ga*CA + lane*2;
  const bf16* bp = bt + (size_t)ga*CA + lane*2;
  bf16* op = outp + (size_t)ga*CA + lane*2;
  op[0] = (bf16)((float)gp[0]*(d0*rs) + (float)bp[0]);
  op[1] = (bf16)((float)gp[1]*(d1*rs) + (float)bp[1]);
}

// ---------------- QKVG projections, LDS-free (q pre-scaled by 1/sqrt(dh)) ----
__global__ __launch_bounds__(256) void qkvg_gemm(const bf16* __restrict__ xa,
    const bf16* __restrict__ wt, const float* __restrict__ bq,
    bf16* __restrict__ outq){
  int tid = threadIdx.x, wave = tid >> 6, lane = tid & 63;
  int l16 = lane & 15, quad = lane >> 4;
  int m0 = blockIdx.x*64;
  int sel = blockIdx.y;
  const bf16* Wt = wt + (size_t)sel*16384;
  const bf16* Ar = xa + (size_t)(m0 + wave*16 + l16)*CA;
  bf16x8 a[4];
  #pragma unroll
  for (int ks = 0; ks < 4; ks++) a[ks] = ldg8(Ar + ks*32 + quad*8);
  f32x4 z = {0.f,0.f,0.f,0.f};
  f32x4 acc[8];
  #pragma unroll
  for (int nt = 0; nt < 8; nt++) acc[nt] = z;
  #pragma unroll
  for (int nt = 0; nt < 8; nt++){
    const bf16* Bp = Wt + (size_t)(nt*16 + l16)*128 + quad*8;
    #pragma unroll
    for (int ks = 0; ks < 4; ks++)
      acc[nt] = mfma16(a[ks], ldg8(Bp + ks*32), acc[nt]);
  }
  const float invs = 0.17677669529663689f;
  #pragma unroll
  for (int nt = 0; nt < 8; nt++)
  #pragma unroll
  for (int r = 0; r < 4; r++){
    int m = m0 + wave*16 + quad*4 + r;
    int n = nt*16 + l16;
    float v = acc[nt][r];
    if (sel == 0) v = (v + bq[n]) * invs;
    if (sel == 3) v = sigmoidf_(v);
    outq[(size_t)m*512 + sel*128 + n] = (bf16)v;
  }
}

// ---------------- windowed attention (bias precomputed) ----------------
__global__ __launch_bounds__(256) void attn_kernel(const bf16* __restrict__ qkvg,
    const bf16* __restrict__ biasg, const float* __restrict__ amask,
    bf16* __restrict__ go){
  __shared__ bf16 Qs[32][136];
  __shared__ bf16 Ks[128][136];   // reused as P buffers
  __shared__ bf16 Vts[128][136];  // V transposed [d][key]
  __shared__ float kmask[128];
  int w = blockIdx.x, b = blockIdx.y;
  int tid = threadIdx.x;
  int wave = tid >> 6, lane = tid & 63, l16 = lane & 15, quad = lane >> 4;
  size_t abase = (size_t)b*NATOM + (size_t)w*NQ;
  int kstart = w*NQ + NQ/2 - NK/2;
  if (tid < 128){
    int pos = kstart + tid;
    kmask[tid] = (pos >= 0 && pos < NATOM) ? amask[(size_t)b*NATOM + pos] : 0.f;
  }
  #pragma unroll
  for (int i = 0; i < 2; i++){
    int c = tid + i*256;
    int row = c >> 4, off = (c & 15)*8;
    uint4 d = *reinterpret_cast<const uint4*>(qkvg + (abase + row)*512 + off);
    *reinterpret_cast<uint4*>(&Qs[row][off]) = d;
  }
  #pragma unroll
  for (int i = 0; i < 8; i++){
    int c = tid + i*256;
    int row = c >> 4, off = (c & 15)*8;
    int ka = kstart + row; ka = ka < 0 ? 0 : (ka > NATOM-1 ? NATOM-1 : ka);
    uint4 d = *reinterpret_cast<const uint4*>(qkvg + ((size_t)b*NATOM + ka)*512 + 128 + off);
    *reinterpret_cast<uint4*>(&Ks[row][off]) = d;
  }
  #pragma unroll
  for (int i = 0; i < 16; i++){
    int c = tid + i*256;
    int row = c >> 5, off = (c & 31)*4;
    int ka = kstart + row; ka = ka < 0 ? 0 : (ka > NATOM-1 ? NATOM-1 : ka);
    uint2 d = *reinterpret_cast<const uint2*>(qkvg + ((size_t)b*NATOM + ka)*512 + 256 + off);
    union { uint2 u; bf16 h[4]; } t; t.u = d;
    Vts[off+0][row] = t.h[0];
    Vts[off+1][row] = t.h[1];
    Vts[off+2][row] = t.h[2];
    Vts[off+3][row] = t.h[3];
  }
  __syncthreads();
  int h = wave;
  f32x4 z4 = {0.f,0.f,0.f,0.f};
  f32x4 sacc[2][8];
  #pragma unroll
  for (int mt = 0; mt < 2; mt++)
    #pragma unroll
    for (int nt = 0; nt < 8; nt++) sacc[mt][nt] = z4;
  {
    bf16x8 bfr[8];
    #pragma unroll
    for (int nt = 0; nt < 8; nt++) bfr[nt] = lds_ld8(&Ks[nt*16 + l16][h*32 + quad*8]);
    #pragma unroll
    for (int mt = 0; mt < 2; mt++){
      bf16x8 a = lds_ld8(&Qs[mt*16 + l16][h*32 + quad*8]);
      #pragma unroll
      for (int nt = 0; nt < 8; nt++) sacc[mt][nt] = mfma16(a, bfr[nt], sacc[mt][nt]);
    }
  }
  // scale already folded into q; add bias + mask
  const bf16* bp = biasg + ((size_t)(b*NWIN + w)*4096)*4;
  #pragma unroll
  for (int mt = 0; mt < 2; mt++)
  #pragma unroll
  for (int r = 0; r < 4; r++){
    int q = mt*16 + quad*4 + r;
    #pragma unroll
    for (int nt = 0; nt < 8; nt++){
      int k = nt*16 + l16;
      float biasv = (float)bp[((size_t)q*128 + k)*4 + h];
      float sv = sacc[mt][nt][r] + biasv;
      sacc[mt][nt][r] = (kmask[k] > 0.f) ? sv : -1e9f;
    }
  }
  float rinv[2][4];
  #pragma unroll
  for (int mt = 0; mt < 2; mt++)
  #pragma unroll
  for (int r = 0; r < 4; r++){
    float mx = -3.0e38f;
    #pragma unroll
    for (int nt = 0; nt < 8; nt++) mx = fmaxf(mx, sacc[mt][nt][r]);
    #pragma unroll
    for (int off = 1; off < 16; off <<= 1) mx = fmaxf(mx, __shfl_xor(mx, off));
    float ss = 0.f;
    #pragma unroll
    for (int nt = 0; nt < 8; nt++){
      float e = __expf(sacc[mt][nt][r] - mx);
      sacc[mt][nt][r] = e; ss += e;
    }
    #pragma unroll
    for (int off = 1; off < 16; off <<= 1) ss += __shfl_xor(ss, off);
    rinv[mt][r] = 1.f/ss;
  }
  __syncthreads();   // all waves done with Ks (QK reads) -> reuse as P
  bf16 (*Ph)[136] = reinterpret_cast<bf16(*)[136]>(&Ks[h*32][0]);
  #pragma unroll
  for (int mt = 0; mt < 2; mt++)
  #pragma unroll
  for (int nt = 0; nt < 8; nt++)
  #pragma unroll
  for (int r = 0; r < 4; r++)
    Ph[mt*16 + quad*4 + r][nt*16 + l16] = (bf16)(sacc[mt][nt][r]*rinv[mt][r]);
  f32x4 oacc[2][2] = {{z4,z4},{z4,z4}};
  #pragma unroll
  for (int kt = 0; kt < 4; kt++){
    bf16x8 a0 = lds_ld8(&Ph[l16][kt*32 + quad*8]);
    bf16x8 a1 = lds_ld8(&Ph[16 + l16][kt*32 + quad*8]);
    bf16x8 b0 = lds_ld8(&Vts[h*32 + l16][kt*32 + quad*8]);
    bf16x8 b1 = lds_ld8(&Vts[h*32 + 16 + l16][kt*32 + quad*8]);
    oacc[0][0] = mfma16(a0, b0, oacc[0][0]);
    oacc[0][1] = mfma16(a0, b1, oacc[0][1]);
    oacc[1][0] = mfma16(a1, b0, oacc[1][0]);
    oacc[1][1] = mfma16(a1, b1, oacc[1][1]);
  }
  #pragma unroll
  for (int mt = 0; mt < 2; mt++)
  #pragma unroll
  for (int nt = 0; nt < 2; nt++)
  #pragma unroll
  for (int r = 0; r < 4; r++){
    int q = mt*16 + quad*4 + r;
    int dcol = h*32 + nt*16 + l16;
    size_t arow = abase + q;
    float gate = (float)qkvg[arow*512 + 384 + dcol];
    go[arow*CA + dcol] = (bf16)(gate * oacc[mt][nt][r]);
  }
}

// -------- residual GEMM + fused next AdaLN: x += g*(A@W); xa = ln(x)*lg+lb ---
template<int K, bool FUSE>
__global__ __launch_bounds__(256) void resid_fused(const bf16* __restrict__ Ain,
    const bf16* __restrict__ Wt, const bf16* __restrict__ gsk,
    float* __restrict__ x,
    const bf16* __restrict__ lng, const bf16* __restrict__ lnb,
    bf16* __restrict__ xaout){
  constexpr int KT = K/32;
  int tid = threadIdx.x, wave = tid >> 6, lane = tid & 63;
  int l16 = lane & 15, quad = lane >> 4;
  int m0 = blockIdx.x*64;
  const bf16* Ar = Ain + (size_t)(m0 + wave*16 + l16)*K;
  bf16x8 a[KT];
  #pragma unroll
  for (int ks = 0; ks < KT; ks++) a[ks] = ldg8(Ar + ks*32 + quad*8);
  f32x4 z = {0.f,0.f,0.f,0.f};
  f32x4 acc[8];
  #pragma unroll
  for (int nt = 0; nt < 8; nt++) acc[nt] = z;
  #pragma unroll
  for (int nt = 0; nt < 8; nt++){
    const bf16* Bp = Wt + (size_t)(nt*16 + l16)*K + quad*8;
    #pragma unroll
    for (int ks = 0; ks < KT; ks++)
      acc[nt] = mfma16(a[ks], ldg8(Bp + ks*32), acc[nt]);
  }
  int mrow = m0 + wave*16 + quad*4;
  #pragma unroll
  for (int nt = 0; nt < 8; nt++)
  #pragma unroll
  for (int r = 0; r < 4; r++){
    size_t idx = (size_t)(mrow + r)*CA + nt*16 + l16;
    float v = x[idx] + (float)gsk[idx]*acc[nt][r];
    x[idx] = v;
    acc[nt][r] = v;
  }
  if constexpr (FUSE){
    #pragma unroll
    for (int r = 0; r < 4; r++){
      float s = 0.f;
      #pragma unroll
      for (int nt = 0; nt < 8; nt++) s += acc[nt][r];
      #pragma unroll
      for (int off = 1; off < 16; off <<= 1) s += __shfl_xor(s, off);
      float mu = s*(1.f/128.f);
      float vs = 0.f;
      #pragma unroll
      for (int nt = 0; nt < 8; nt++){
        float d = acc[nt][r] - mu; vs += d*d;
      }
      #pragma unroll
      for (int off = 1; off < 16; off <<= 1) vs += __shfl_xor(vs, off);
      float rs = rsqrtf(vs*(1.f/128.f) + 1e-5f);
      #pragma unroll
      for (int nt = 0; nt < 8; nt++){
        size_t idx = (size_t)(mrow + r)*CA + nt*16 + l16;
        float xn = (acc[nt][r] - mu)*rs;
        xaout[idx] = (bf16)((float)lng[idx]*xn + (float)lnb[idx]);
      }
    }
  }
}

// ---------------- SwiGLU first stage, LDS-free ----------------
__global__ __launch_bounds__(256) void t12_gemm(const bf16* __restrict__ xt,
    const bf16* __restrict__ Wt1, const bf16* __restrict__ Wt2,
    bf16* __restrict__ hsw){
  int tid = threadIdx.x, wave = tid >> 6, lane = tid & 63;
  int l16 = lane & 15, quad = lane >> 4;
  int m0 = blockIdx.x*64;
  int n0 = blockIdx.y*128;
  const bf16* Ar = xt + (size_t)(m0 + wave*16 + l16)*CA;
  bf16x8 a[4];
  #pragma unroll
  for (int ks = 0; ks < 4; ks++) a[ks] = ldg8(Ar + ks*32 + quad*8);
  f32x4 z = {0.f,0.f,0.f,0.f};
  f32x4 acc1[8], acc2[8];
  #pragma unroll
  for (int nt = 0; nt < 8; nt++){ acc1[nt] = z; acc2[nt] = z; }
  #pragma unroll
  for (int nt = 0; nt < 8; nt++){
    const bf16* Bp1 = Wt1 + (size_t)(n0 + nt*16 + l16)*128 + quad*8;
    const bf16* Bp2 = Wt2 + (size_t)(n0 + nt*16 + l16)*128 + quad*8;
    #pragma unroll
    for (int ks = 0; ks < 4; ks++){
      acc1[nt] = mfma16(a[ks], ldg8(Bp1 + ks*32), acc1[nt]);
      acc2[nt] = mfma16(a[ks], ldg8(Bp2 + ks*32), acc2[nt]);
    }
  }
  #pragma unroll
  for (int nt = 0; nt < 8; nt++)
  #pragma unroll
  for (int r = 0; r < 4; r++){
    int m = m0 + wave*16 + quad*4 + r;
    int n = n0 + nt*16 + l16;
    float v1 = acc1[nt][r];
    float v2 = acc2[nt][r];
    hsw[(size_t)m*(2*CA) + n] = (bf16)(v1*sigmoidf_(v1)*v2);
  }
}

// ---------------- final LN + projection to 3 ----------------
__global__ __launch_bounds__(256) void final_kernel(const float* __restrict__ x,
    const float* __restrict__ amask, const float* __restrict__ lg,
    const float* __restrict__ lb, const float* __restrict__ Wout,
    float* __restrict__ outp){
  int ga = blockIdx.x * 4 + (threadIdx.x >> 6);
  int lane = threadIdx.x & 63;
  float2 xv = *reinterpret_cast<const float2*>(x + (size_t)ga*CA + lane*2);
  float m = amask[ga];
  xv.x *= m; xv.y *= m;
  float s = red_sum64(xv.x + xv.y);
  float mu = s * (1.f/128.f);
  float d0 = xv.x - mu, d1 = xv.y - mu;
  float vs = red_sum64(d0*d0 + d1*d1);
  float rs = rsqrtf(vs*(1.f/128.f) + 1e-5f);
  int c = lane*2;
  float xn0 = d0*rs*lg[c]   + lb[c];
  float xn1 = d1*rs*lg[c+1] + lb[c+1];
  float p0 = xn0*Wout[c*3+0] + xn1*Wout[(c+1)*3+0];
  float p1 = xn0*Wout[c*3+1] + xn1*Wout[(c+1)*3+1];
  float p2 = xn0*Wout[c*3+2] + xn1*Wout[(c+1)*3+2];
  p0 = red_sum64(p0); p1 = red_sum64(p1); p2 = red_sum64(p2);
  if (lane == 0){
    outp[(size_t)ga*3 + 0] = p0;
    outp[(size_t)ga*3 + 1] = p1;
    outp[(size_t)ga*3 + 2] = p2;
  }
}

extern "C" void kernel_launch(void* const* d_in, const int* in_sizes, int n_in,
                              void* d_out, int out_size, void* d_ws, size_t ws_size,
                              hipStream_t stream){
  (void)in_sizes; (void)n_in; (void)out_size; (void)ws_size;
  const float* a     = (const float*)d_in[0];
  const float* ef    = (const float*)d_in[2];
  const float* p_lm  = (const float*)d_in[3];
  const float* amask = (const float*)d_in[4];
  const int*   a2t   = (const int*)d_in[5];
  const float* Wa    = (const float*)d_in[6];
  const float* lnq_g = (const float*)d_in[7];
  const float* lnq_b = (const float*)d_in[8];
  const float* Wout  = (const float*)d_in[9];
  const float* ag_w  = (const float*)d_in[10];
  const float* ag_b  = (const float*)d_in[11];
  const float* ab_w  = (const float*)d_in[12];
  const float* wq    = (const float*)d_in[13];
  const float* bq    = (const float*)d_in[14];
  const float* wk    = (const float*)d_in[15];
  const float* wv    = (const float*)d_in[16];
  const float* pg    = (const float*)d_in[17];
  const float* pb    = (const float*)d_in[18];
  const float* wpb   = (const float*)d_in[19];
  const float* wg    = (const float*)d_in[20];
  const float* wo    = (const float*)d_in[21];
  const float* sk_w  = (const float*)d_in[22];
  const float* sk_b  = (const float*)d_in[23];
  const float* tg_w  = (const float*)d_in[24];
  const float* tg_b  = (const float*)d_in[25];
  const float* tb_w  = (const float*)d_in[26];
  const float* wt1   = (const float*)d_in[27];
  const float* wt2   = (const float*)d_in[28];
  const float* wto   = (const float*)d_in[29];
  const float* tk_w  = (const float*)d_in[30];
  const float* tk_b  = (const float*)d_in[31];
  float* out = (float*)d_out;
  char* ws = (char*)d_ws;

  const size_t OFF_X    = 0;
  const size_t OFF_SNC  = OFF_X    + (size_t)MTOT*CA*4;
  const size_t OFF_TVAL = OFF_SNC  + (size_t)MTOT*CA*2;
  const size_t OFF_AW   = OFF_TVAL + (size_t)MTOT*4;
  const size_t OFF_CS   = OFF_AW   + (size_t)BB*NTOK*CA*4;
  const size_t OFF_WT   = OFF_CS   + 18*CA*4 + 256;
  const size_t OFF_COND = OFF_WT   + (size_t)WT_TOTAL*2 + 256;
  const size_t OFF_XA   = OFF_COND + (size_t)18*CSZ*2;
  const size_t OFF_QKVG = OFF_XA   + (size_t)MTOT*CA*2;
  const size_t OFF_HSW  = OFF_QKVG + (size_t)MTOT*512*2;
  const size_t OFF_GO   = OFF_HSW  + (size_t)MTOT*256*2;
  const size_t OFF_BIAS = OFF_GO   + (size_t)MTOT*CA*2;

  float* x    = (float*)(ws + OFF_X);
  bf16*  snc  = (bf16*)(ws + OFF_SNC);
  float* tval = (float*)(ws + OFF_TVAL);
  float* aW   = (float*)(ws + OFF_AW);
  float* cs   = (float*)(ws + OFF_CS);
  bf16*  wt   = (bf16*)(ws + OFF_WT);
  bf16*  cond = (bf16*)(ws + OFF_COND);
  bf16*  xa   = (bf16*)(ws + OFF_XA);
  bf16*  qkvg = (bf16*)(ws + OFF_QKVG);
  bf16*  hsw  = (bf16*)(ws + OFF_HSW);
  bf16*  go   = (bf16*)(ws + OFF_GO);
  bf16*  biasg= (bf16*)(ws + OFF_BIAS);

  token_gemm<<<BB*NTOK, 128, 0, stream>>>(a, Wa, aW);
  build_x0<<<MTOT/4, 256, 0, stream>>>(aW, ef, amask, a2t, x, snc, tval);
  wconv<<<96, 256, 0, stream>>>(ag_w, ab_w, sk_w, tg_w, tb_w, tk_w,
      wq, wk, wv, wg, wo, wt1, wt2, wto, wt);
  colsums<<<18, 128, 0, stream>>>(ag_w, ab_w, sk_w, tg_w, tb_w, tk_w, cs);
  cond_all<<<dim3(MTOT/64, 3), 256, 0, stream>>>(snc, tval, wt + WT_COND_OFF,
      ag_b, sk_b, tg_b, tk_b, cs, cond);
  bias_all<<<dim3(NWIN, BB), 256, 0, stream>>>(p_lm, pg, pb, wpb, biasg);
  adaln_kernel<<<MTOT/4, 256, 0, stream>>>(x, cond, cond + CSZ, xa);

  for (int i = 0; i < 3; i++){
    qkvg_gemm<<<dim3(MTOT/64, 4), 256, 0, stream>>>(xa,
        wt + WT_QKVG_OFF + (size_t)i*4*16384, bq + (size_t)i*CA, qkvg);
    attn_kernel<<<dim3(NWIN, BB), 256, 0, stream>>>(qkvg,
        biasg + (size_t)i*BIAS_I, amask, go);
    resid_fused<128,true><<<MTOT/64, 256, 0, stream>>>(go,
        wt + WT_WO_OFF + (size_t)i*16384, cond + (size_t)(i*6+2)*CSZ, x,
        cond + (size_t)(i*6+3)*CSZ, cond + (size_t)(i*6+4)*CSZ, xa);
    t12_gemm<<<dim3(MTOT/64, 2), 256, 0, stream>>>(xa,
        wt + WT_T12_OFF + (size_t)(2*i)*32768,
        wt + WT_T12_OFF + (size_t)(2*i+1)*32768, hsw);
    if (i < 2)
      resid_fused<256,true><<<MTOT/64, 256, 0, stream>>>(hsw,
          wt + WT_WTO_OFF + (size_t)i*32768, cond + (size_t)(i*6+5)*CSZ, x,
          cond + (size_t)((i+1)*6+0)*CSZ, cond + (size_t)((i+1)*6+1)*CSZ, xa);
    else
      resid_fused<256,false><<<MTOT/64, 256, 0, stream>>>(hsw,
          wt + WT_WTO_OFF + (size_t)i*32768, cond + (size_t)(i*6+5)*CSZ, x,
          nullptr, nullptr, nullptr);
  }
  final_kernel<<<MTOT/4, 256, 0, stream>>>(x, amask, lnq_g, lnq_b, Wout, out);
}

// Round 3
// 1034.697 us; speedup vs baseline: 1.2349x; 1.2349x over previous
//
#include <hip/hip_runtime.h>
#include <hip/hip_bf16.h>

typedef __bf16 bf16;
typedef __bf16 bf16x8 __attribute__((ext_vector_type(8)));
typedef float f32x4 __attribute__((ext_vector_type(4)));

#define DEV static __device__ __forceinline__

#define BB 2
#define NTOK 512
#define NATOM 16384
#define CT 384
#define CA 128
#define CP 16
#define CS 384
#define NQ 32
#define NK 128
#define NH 4
#define DH 32
#define NWIN 512
#define MTOT (BB*NATOM) /* 32768 */
#define CSZ ((size_t)MTOT*CA)

// transposed-bf16 weight arena offsets (elements)
#define WT_COND_OFF 0        /* 18 x [128][128] */
#define WT_QKVG_OFF 294912   /* 12 x [128][128] */
#define WT_WO_OFF   491520   /* 3 x [128][128]  */
#define WT_T12_OFF  540672   /* 6 x [256][128]  */
#define WT_WTO_OFF  737280   /* 3 x [128][256]  */
#define WT_TOTAL    835584
#define BIAS_I      16777216 /* bias elems per block-i: 2*512*4096*4 */

DEV bf16x8 lds_ld8(const bf16* p){
  union { uint2 u[2]; bf16x8 v; } t;
  t.u[0] = *reinterpret_cast<const uint2*>(p);
  t.u[1] = *reinterpret_cast<const uint2*>(p + 4);
  return t.v;
}
DEV bf16x8 lds_ld16(const bf16* p){
  union { uint4 u; bf16x8 v; } t;
  t.u = *reinterpret_cast<const uint4*>(p);
  return t.v;
}
DEV bf16x8 ldg8(const bf16* p){
  union { uint4 u; bf16x8 v; } t;
  t.u = *reinterpret_cast<const uint4*>(p);
  return t.v;
}
DEV f32x4 mfma16(bf16x8 a, bf16x8 b, f32x4 c){
  return __builtin_amdgcn_mfma_f32_16x16x32_bf16(a, b, c, 0, 0, 0);
}
DEV float sigmoidf_(float x){ return 1.f/(1.f + __expf(-x)); }
DEV float red_sum64(float v){
  #pragma unroll
  for (int off = 1; off < 64; off <<= 1) v += __shfl_xor(v, off);
  return v;
}

// ============ LDS-staged GEMM engine: BM=128 (4 waves x 32 rows), N=128 ======
// Weight in global is bf16 [n][K] (pre-transposed). LDS row stride = K+8
// (2-way bank aliasing only, free). A held in registers.
template<int KT>   // K = KT*32
DEV void stageB_load(const bf16* __restrict__ Bg, uint4* v, int tid){
  #pragma unroll
  for (int i = 0; i < KT*2; i++)
    v[i] = *reinterpret_cast<const uint4*>(Bg + (size_t)(tid + i*256)*8);
}
template<int KT>
DEV void stageB_write(bf16* Bs, const uint4* v, int tid){
  const int CPR = KT*4;            // 16B chunks per row
  const int STR = KT*32 + 8;
  #pragma unroll
  for (int i = 0; i < KT*2; i++){
    int c = tid + i*256;
    int row = c/CPR, koff = (c%CPR)*8;
    *reinterpret_cast<uint4*>(Bs + row*STR + koff) = v[i];
  }
}
template<int KT>
DEV void stage_direct(bf16* Bs, const bf16* __restrict__ Bg, int tid){
  uint4 v[KT*2];
  stageB_load<KT>(Bg, v, tid);
  stageB_write<KT>(Bs, v, tid);
}
template<int KT>
DEV void loadA2(const bf16* __restrict__ A, int row0, int l16, int quad,
                bf16x8* a0, bf16x8* a1){
  const bf16* r0 = A + (size_t)(row0 + l16)*(KT*32) + quad*8;
  const bf16* r1 = r0 + (size_t)16*(KT*32);
  #pragma unroll
  for (int ks = 0; ks < KT; ks++){
    a0[ks] = ldg8(r0 + ks*32);
    a1[ks] = ldg8(r1 + ks*32);
  }
}
template<int KT>
DEV void mma_blockT(const bf16* Bs, const bf16x8* a0, const bf16x8* a1,
                    f32x4* acc0, f32x4* acc1, int l16, int quad){
  const int STR = KT*32 + 8;
  #pragma unroll
  for (int nt = 0; nt < 8; nt++){
    const bf16* bp = Bs + (nt*16 + l16)*STR + quad*8;
    #pragma unroll
    for (int ks = 0; ks < KT; ks++){
      bf16x8 b = lds_ld16(bp + ks*32);
      acc0[nt] = mfma16(a0[ks], b, acc0[nt]);
      acc1[nt] = mfma16(a1[ks], b, acc1[nt]);
    }
  }
}

// ---------------- weight prep: f32 [K][N] -> bf16 [N][K] ----------------
__global__ __launch_bounds__(256) void wconv(
    const float* ag, const float* ab, const float* sk,
    const float* tg, const float* tb, const float* tk,
    const float* wq, const float* wk, const float* wv, const float* wg,
    const float* wo, const float* wt1, const float* wt2, const float* wto,
    bf16* __restrict__ wt){
  __shared__ __align__(16) bf16 T[64][264];
  int s = blockIdx.x;
  int mat, nslab;
  if (s < 66){ mat = s >> 1; nslab = s & 1; }
  else if (s < 90){ mat = 33 + (s-66)/4; nslab = (s-66)&3; }
  else { mat = 39 + ((s-90)>>1); nslab = (s-90)&1; }
  const float* src; int K, N; size_t dst;
  if (mat < 18){ int i = mat/6, t = mat - i*6;
    const float* base = t==0?ag:t==1?ab:t==2?sk:t==3?tg:t==4?tb:tk;
    src = base + (size_t)i*CS*CA; K=128; N=128; dst = WT_COND_OFF + (size_t)mat*16384; }
  else if (mat < 30){ int q = mat-18; int i=q>>2, sx=q&3;
    const float* base = sx==0?wq:sx==1?wk:sx==2?wv:wg;
    src = base + (size_t)i*16384; K=128; N=128; dst = WT_QKVG_OFF + (size_t)q*16384; }
  else if (mat < 33){ src = wo + (size_t)(mat-30)*16384; K=128; N=128;
    dst = WT_WO_OFF + (size_t)(mat-30)*16384; }
  else if (mat < 39){ int q = mat-33; int i=q>>1, sx=q&1;
    src = (sx? wt2 : wt1) + (size_t)i*32768; K=128; N=256;
    dst = WT_T12_OFF + (size_t)q*32768; }
  else { src = wto + (size_t)(mat-39)*32768; K=256; N=128;
    dst = WT_WTO_OFF + (size_t)(mat-39)*32768; }
  int n0 = nslab*64;
  int tid = threadIdx.x;
  for (int c = tid; c < K*16; c += 256){
    int k = c >> 4, nq = c & 15;
    float4 v = *reinterpret_cast<const float4*>(src + (size_t)k*N + n0 + nq*4);
    T[nq*4+0][k] = (bf16)v.x; T[nq*4+1][k] = (bf16)v.y;
    T[nq*4+2][k] = (bf16)v.z; T[nq*4+3][k] = (bf16)v.w;
  }
  __syncthreads();
  int KQ = K >> 3;
  for (int c = tid; c < 64*KQ; c += 256){
    int n = c / KQ, kq = c - n*KQ;
    uint4 d = *reinterpret_cast<const uint4*>(&T[n][kq*8]);
    *reinterpret_cast<uint4*>(wt + dst + (size_t)(n0+n)*K + kq*8) = d;
  }
}

// ---------------- small prologue kernels ----------------
__global__ __launch_bounds__(128) void token_gemm(const float* __restrict__ a,
    const float* __restrict__ Wa, float* __restrict__ aW){
  __shared__ float arow[CT];
  int row = blockIdx.x;
  for (int j = threadIdx.x; j < CT; j += 128) arow[j] = a[(size_t)row*CT + j];
  __syncthreads();
  int c = threadIdx.x;
  float s = 0.f;
  for (int j = 0; j < CT; j++) s += arow[j] * Wa[(size_t)j*CA + c];
  aW[(size_t)row*CA + c] = s;
}

__global__ __launch_bounds__(256) void build_x0(const float* __restrict__ aW,
    const float* __restrict__ ef, const float* __restrict__ amask,
    const int* __restrict__ a2t, float* __restrict__ x,
    bf16* __restrict__ snc, float* __restrict__ tval){
  int ga = blockIdx.x * 4 + (threadIdx.x >> 6);
  int lane = threadIdx.x & 63;
  int b = ga >> 14;
  int tok = a2t[ga];
  float2 av = *reinterpret_cast<const float2*>(aW + ((size_t)(b*NTOK + tok))*CA + lane*2);
  float2 ev = *reinterpret_cast<const float2*>(ef + (size_t)ga*CA + lane*2);
  float m = amask[ga];
  *reinterpret_cast<float2*>(x + (size_t)ga*CA + lane*2) =
      make_float2((av.x + ev.x)*m, (av.y + ev.y)*m);
  float s = red_sum64(ev.x + ev.y);
  float mu = s * (1.f/384.f);
  float d0 = ev.x - mu, d1 = ev.y - mu;
  float vs = red_sum64(d0*d0 + d1*d1);
  float var = (vs + 256.f*mu*mu) * (1.f/384.f);
  float rs = rsqrtf(var + 1e-5f);
  bf16* sp = snc + (size_t)ga*CA + lane*2;
  sp[0] = (bf16)(d0*rs); sp[1] = (bf16)(d1*rs);
  if (lane == 0) tval[ga] = -mu*rs;
}

__global__ __launch_bounds__(128) void colsums(const float* ag, const float* ab,
    const float* sk, const float* tg, const float* tb, const float* tk,
    float* __restrict__ cs){
  int mat = blockIdx.x;              // 0..17 = i*6+t
  int i = mat / 6, t = mat % 6;
  const float* base = t==0?ag : t==1?ab : t==2?sk : t==3?tg : t==4?tb : tk;
  const float* W = base + (size_t)i*CS*CA;
  int c = threadIdx.x;
  float s = 0.f;
  for (int k = CA; k < CS; k++) s += W[(size_t)k*CA + c];
  cs[(size_t)mat*CA + c] = s;
}

// ---------------- all conditioning GEMMs (LDS-staged, double-buffered) ------
__global__ __launch_bounds__(256) void cond_all(const bf16* __restrict__ snc,
    const float* __restrict__ tval, const bf16* __restrict__ wtc,
    const float* __restrict__ ag_b, const float* __restrict__ sk_b,
    const float* __restrict__ tg_b, const float* __restrict__ tk_b,
    const float* __restrict__ cs, bf16* __restrict__ cond){
  __shared__ bf16 Bs[2][128*136];
  int tid = threadIdx.x, wave = tid >> 6, lane = tid & 63;
  int l16 = lane & 15, quad = lane >> 4;
  int m0 = blockIdx.x*128; int i = blockIdx.y;
  int mrow = m0 + wave*32;
  bf16x8 a0[4], a1[4];
  loadA2<4>(snc, mrow, l16, quad, a0, a1);
  float tv[2][4];
  #pragma unroll
  for (int s = 0; s < 2; s++)
  #pragma unroll
  for (int r = 0; r < 4; r++) tv[s][r] = tval[mrow + s*16 + quad*4 + r];
  uint4 stg[8];
  stageB_load<4>(wtc + (size_t)(i*6)*16384, stg, tid);
  stageB_write<4>(Bs[0], stg, tid);
  __syncthreads();
  for (int t = 0; t < 6; t++){
    if (t < 5) stageB_load<4>(wtc + (size_t)(i*6+t+1)*16384, stg, tid);
    f32x4 z = {0.f,0.f,0.f,0.f};
    f32x4 acc0[8], acc1[8];
    #pragma unroll
    for (int nt = 0; nt < 8; nt++){ acc0[nt] = z; acc1[nt] = z; }
    mma_blockT<4>(Bs[t&1], a0, a1, acc0, acc1, l16, quad);
    if (t < 5) stageB_write<4>(Bs[(t+1)&1], stg, tid);
    __syncthreads();
    const float* csr = cs + (size_t)(i*6+t)*CA;
    const float* bias = t==0 ? ag_b + (size_t)i*CA : t==2 ? sk_b + (size_t)i*CA
                      : t==3 ? tg_b + (size_t)i*CA : t==5 ? tk_b + (size_t)i*CA : nullptr;
    bool sig = (t==0)||(t==2)||(t==3)||(t==5);
    bf16* op = cond + (size_t)(i*6+t)*CSZ;
    #pragma unroll
    for (int s = 0; s < 2; s++)
    #pragma unroll
    for (int nt = 0; nt < 8; nt++)
    #pragma unroll
    for (int r = 0; r < 4; r++){
      int m = mrow + s*16 + quad*4 + r;
      int n = nt*16 + l16;
      float v = (s ? acc1 : acc0)[nt][r] + tv[s][r]*csr[n];
      if (bias) v += bias[n];
      if (sig)  v = sigmoidf_(v);
      op[(size_t)m*CA + n] = (bf16)v;
    }
  }
}

// ---------------- pair bias for all 3 blocks, SINGLE p_lm pass ----------------
__global__ __launch_bounds__(256) void bias_all(const float* __restrict__ p_lm,
    const float* __restrict__ pg, const float* __restrict__ pb,
    const float* __restrict__ wpb, bf16* __restrict__ biasg){
  __shared__ f32x4 wjS[3][16];
  __shared__ f32x4 wsumS[3], ccS[3];
  int w = blockIdx.x, b = blockIdx.y;
  int tid = threadIdx.x;
  if (tid < 48){
    int i = tid >> 4, j = tid & 15;
    f32x4 wp = *reinterpret_cast<const f32x4*>(wpb + (size_t)(i*16+j)*4);
    wjS[i][j] = pg[i*16+j]*wp;
  }
  __syncthreads();
  if (tid < 3){
    f32x4 s = {0.f,0.f,0.f,0.f}, c = {0.f,0.f,0.f,0.f};
    for (int j = 0; j < 16; j++){
      s += wjS[tid][j];
      f32x4 wp = *reinterpret_cast<const f32x4*>(wpb + (size_t)(tid*16+j)*4);
      c += pb[tid*16+j]*wp;
    }
    wsumS[tid] = s; ccS[tid] = c;
  }
  __syncthreads();
  size_t pbase = (size_t)(b*NWIN + w)*(NQ*NK*CP);
  size_t obase = (size_t)(b*NWIN + w)*4096*4;
  #pragma unroll 1
  for (int t = 0; t < 16; t++){
    int pid = t*256 + tid;
    const float* pp = p_lm + pbase + (size_t)pid*16;
    float4 p0 = *reinterpret_cast<const float4*>(pp);
    float4 p1 = *reinterpret_cast<const float4*>(pp + 4);
    float4 p2 = *reinterpret_cast<const float4*>(pp + 8);
    float4 p3 = *reinterpret_cast<const float4*>(pp + 12);
    float sm = p0.x+p0.y+p0.z+p0.w + p1.x+p1.y+p1.z+p1.w
             + p2.x+p2.y+p2.z+p2.w + p3.x+p3.y+p3.z+p3.w;
    float sq = p0.x*p0.x+p0.y*p0.y+p0.z*p0.z+p0.w*p0.w
             + p1.x*p1.x+p1.y*p1.y+p1.z*p1.z+p1.w*p1.w
             + p2.x*p2.x+p2.y*p2.y+p2.z*p2.z+p2.w*p2.w
             + p3.x*p3.x+p3.y*p3.y+p3.z*p3.z+p3.w*p3.w;
    float mu = sm * (1.f/16.f);
    float var = fmaxf(sq*(1.f/16.f) - mu*mu, 0.f);
    float rsg = rsqrtf(var + 1e-5f);
    #pragma unroll
    for (int i = 0; i < 3; i++){
      f32x4 dw = {0.f,0.f,0.f,0.f};
      dw += p0.x*wjS[i][0];  dw += p0.y*wjS[i][1];  dw += p0.z*wjS[i][2];  dw += p0.w*wjS[i][3];
      dw += p1.x*wjS[i][4];  dw += p1.y*wjS[i][5];  dw += p1.z*wjS[i][6];  dw += p1.w*wjS[i][7];
      dw += p2.x*wjS[i][8];  dw += p2.y*wjS[i][9];  dw += p2.z*wjS[i][10]; dw += p2.w*wjS[i][11];
      dw += p3.x*wjS[i][12]; dw += p3.y*wjS[i][13]; dw += p3.z*wjS[i][14]; dw += p3.w*wjS[i][15];
      f32x4 b4 = rsg*(dw - mu*wsumS[i]) + ccS[i];
      union { uint2 u; bf16 hh[4]; } tb;
      tb.hh[0] = (bf16)b4.x; tb.hh[1] = (bf16)b4.y;
      tb.hh[2] = (bf16)b4.z; tb.hh[3] = (bf16)b4.w;
      *reinterpret_cast<uint2*>(biasg + (size_t)i*BIAS_I + obase + (size_t)pid*4) = tb.u;
    }
  }
}

// ---------------- AdaLN (standalone, used once for block 0) ----------------
__global__ __launch_bounds__(256) void adaln_kernel(const float* __restrict__ x,
    const bf16* __restrict__ g, const bf16* __restrict__ bt, bf16* __restrict__ outp){
  int ga = blockIdx.x * 4 + (threadIdx.x >> 6);
  int lane = threadIdx.x & 63;
  float2 xv = *reinterpret_cast<const float2*>(x + (size_t)ga*CA + lane*2);
  float s = red_sum64(xv.x + xv.y);
  float mu = s * (1.f/128.f);
  float d0 = xv.x - mu, d1 = xv.y - mu;
  float vs = red_sum64(d0*d0 + d1*d1);
  float rs = rsqrtf(vs*(1.f/128.f) + 1e-5f);
  const bf16* gp = g  + (size_t)ga*CA + lane*2;
  const bf16* bp = bt + (size_t)ga*CA + lane*2;
  bf16* op = outp + (size_t)ga*CA + lane*2;
  op[0] = (bf16)((float)gp[0]*(d0*rs) + (float)bp[0]);
  op[1] = (bf16)((float)gp[1]*(d1*rs) + (float)bp[1]);
}

// ---------------- QKVG projections (LDS-staged, 4-matrix loop) --------------
__global__ __launch_bounds__(256) void qkvg_gemm(const bf16* __restrict__ xa,
    const bf16* __restrict__ wt, const float* __restrict__ bq,
    bf16* __restrict__ outq){
  __shared__ bf16 Bs[2][128*136];
  int tid = threadIdx.x, wave = tid >> 6, lane = tid & 63;
  int l16 = lane & 15, quad = lane >> 4;
  int m0 = blockIdx.x*128;
  int mrow = m0 + wave*32;
  bf16x8 a0[4], a1[4];
  loadA2<4>(xa, mrow, l16, quad, a0, a1);
  uint4 stg[8];
  stageB_load<4>(wt, stg, tid);
  stageB_write<4>(Bs[0], stg, tid);
  __syncthreads();
  const float invs = 0.17677669529663689f;
  for (int sel = 0; sel < 4; sel++){
    if (sel < 3) stageB_load<4>(wt + (size_t)(sel+1)*16384, stg, tid);
    f32x4 z = {0.f,0.f,0.f,0.f};
    f32x4 acc0[8], acc1[8];
    #pragma unroll
    for (int nt = 0; nt < 8; nt++){ acc0[nt] = z; acc1[nt] = z; }
    mma_blockT<4>(Bs[sel&1], a0, a1, acc0, acc1, l16, quad);
    if (sel < 3) stageB_write<4>(Bs[(sel+1)&1], stg, tid);
    __syncthreads();
    #pragma unroll
    for (int s = 0; s < 2; s++)
    #pragma unroll
    for (int nt = 0; nt < 8; nt++)
    #pragma unroll
    for (int r = 0; r < 4; r++){
      int m = mrow + s*16 + quad*4 + r;
      int n = nt*16 + l16;
      float v = (s ? acc1 : acc0)[nt][r];
      if (sel == 0) v = (v + bq[n]) * invs;
      if (sel == 3) v = sigmoidf_(v);
      outq[(size_t)m*512 + sel*128 + n] = (bf16)v;
    }
  }
}

// ---------------- windowed attention (bias precomputed) ----------------
__global__ __launch_bounds__(256) void attn_kernel(const bf16* __restrict__ qkvg,
    const bf16* __restrict__ biasg, const float* __restrict__ amask,
    bf16* __restrict__ go){
  __shared__ bf16 Qs[32][136];
  __shared__ bf16 Ks[128][136];   // reused as P buffers
  __shared__ bf16 Vts[128][136];  // V transposed [d][key]
  __shared__ float kmask[128];
  int w = blockIdx.x, b = blockIdx.y;
  int tid = threadIdx.x;
  int wave = tid >> 6, lane = tid & 63, l16 = lane & 15, quad = lane >> 4;
  size_t abase = (size_t)b*NATOM + (size_t)w*NQ;
  int kstart = w*NQ + NQ/2 - NK/2;
  if (tid < 128){
    int pos = kstart + tid;
    kmask[tid] = (pos >= 0 && pos < NATOM) ? amask[(size_t)b*NATOM + pos] : 0.f;
  }
  #pragma unroll
  for (int i = 0; i < 2; i++){
    int c = tid + i*256;
    int row = c >> 4, off = (c & 15)*8;
    uint4 d = *reinterpret_cast<const uint4*>(qkvg + (abase + row)*512 + off);
    *reinterpret_cast<uint4*>(&Qs[row][off]) = d;
  }
  #pragma unroll
  for (int i = 0; i < 8; i++){
    int c = tid + i*256;
    int row = c >> 4, off = (c & 15)*8;
    int ka = kstart + row; ka = ka < 0 ? 0 : (ka > NATOM-1 ? NATOM-1 : ka);
    uint4 d = *reinterpret_cast<const uint4*>(qkvg + ((size_t)b*NATOM + ka)*512 + 128 + off);
    *reinterpret_cast<uint4*>(&Ks[row][off]) = d;
  }
  #pragma unroll
  for (int i = 0; i < 16; i++){
    int c = tid + i*256;
    int row = c >> 5, off = (c & 31)*4;
    int ka = kstart + row; ka = ka < 0 ? 0 : (ka > NATOM-1 ? NATOM-1 : ka);
    uint2 d = *reinterpret_cast<const uint2*>(qkvg + ((size_t)b*NATOM + ka)*512 + 256 + off);
    union { uint2 u; bf16 h[4]; } t; t.u = d;
    Vts[off+0][row] = t.h[0];
    Vts[off+1][row] = t.h[1];
    Vts[off+2][row] = t.h[2];
    Vts[off+3][row] = t.h[3];
  }
  __syncthreads();
  int h = wave;
  f32x4 z4 = {0.f,0.f,0.f,0.f};
  f32x4 sacc[2][8];
  #pragma unroll
  for (int mt = 0; mt < 2; mt++)
    #pragma unroll
    for (int nt = 0; nt < 8; nt++) sacc[mt][nt] = z4;
  {
    bf16x8 bfr[8];
    #pragma unroll
    for (int nt = 0; nt < 8; nt++) bfr[nt] = lds_ld8(&Ks[nt*16 + l16][h*32 + quad*8]);
    #pragma unroll
    for (int mt = 0; mt < 2; mt++){
      bf16x8 a = lds_ld8(&Qs[mt*16 + l16][h*32 + quad*8]);
      #pragma unroll
      for (int nt = 0; nt < 8; nt++) sacc[mt][nt] = mfma16(a, bfr[nt], sacc[mt][nt]);
    }
  }
  const bf16* bp = biasg + ((size_t)(b*NWIN + w)*4096)*4;
  #pragma unroll
  for (int mt = 0; mt < 2; mt++)
  #pragma unroll
  for (int r = 0; r < 4; r++){
    int q = mt*16 + quad*4 + r;
    #pragma unroll
    for (int nt = 0; nt < 8; nt++){
      int k = nt*16 + l16;
      float biasv = (float)bp[((size_t)q*128 + k)*4 + h];
      float sv = sacc[mt][nt][r] + biasv;
      sacc[mt][nt][r] = (kmask[k] > 0.f) ? sv : -1e9f;
    }
  }
  float rinv[2][4];
  #pragma unroll
  for (int mt = 0; mt < 2; mt++)
  #pragma unroll
  for (int r = 0; r < 4; r++){
    float mx = -3.0e38f;
    #pragma unroll
    for (int nt = 0; nt < 8; nt++) mx = fmaxf(mx, sacc[mt][nt][r]);
    #pragma unroll
    for (int off = 1; off < 16; off <<= 1) mx = fmaxf(mx, __shfl_xor(mx, off));
    float ss = 0.f;
    #pragma unroll
    for (int nt = 0; nt < 8; nt++){
      float e = __expf(sacc[mt][nt][r] - mx);
      sacc[mt][nt][r] = e; ss += e;
    }
    #pragma unroll
    for (int off = 1; off < 16; off <<= 1) ss += __shfl_xor(ss, off);
    rinv[mt][r] = 1.f/ss;
  }
  __syncthreads();   // all waves done with Ks (QK reads) -> reuse as P
  bf16 (*Ph)[136] = reinterpret_cast<bf16(*)[136]>(&Ks[h*32][0]);
  #pragma unroll
  for (int mt = 0; mt < 2; mt++)
  #pragma unroll
  for (int nt = 0; nt < 8; nt++)
  #pragma unroll
  for (int r = 0; r < 4; r++)
    Ph[mt*16 + quad*4 + r][nt*16 + l16] = (bf16)(sacc[mt][nt][r]*rinv[mt][r]);
  f32x4 oacc[2][2] = {{z4,z4},{z4,z4}};
  #pragma unroll
  for (int kt = 0; kt < 4; kt++){
    bf16x8 a0 = lds_ld8(&Ph[l16][kt*32 + quad*8]);
    bf16x8 a1 = lds_ld8(&Ph[16 + l16][kt*32 + quad*8]);
    bf16x8 b0 = lds_ld8(&Vts[h*32 + l16][kt*32 + quad*8]);
    bf16x8 b1 = lds_ld8(&Vts[h*32 + 16 + l16][kt*32 + quad*8]);
    oacc[0][0] = mfma16(a0, b0, oacc[0][0]);
    oacc[0][1] = mfma16(a0, b1, oacc[0][1]);
    oacc[1][0] = mfma16(a1, b0, oacc[1][0]);
    oacc[1][1] = mfma16(a1, b1, oacc[1][1]);
  }
  #pragma unroll
  for (int mt = 0; mt < 2; mt++)
  #pragma unroll
  for (int nt = 0; nt < 2; nt++)
  #pragma unroll
  for (int r = 0; r < 4; r++){
    int q = mt*16 + quad*4 + r;
    int dcol = h*32 + nt*16 + l16;
    size_t arow = abase + q;
    float gate = (float)qkvg[arow*512 + 384 + dcol];
    go[arow*CA + dcol] = (bf16)(gate * oacc[mt][nt][r]);
  }
}

// -------- residual GEMM + fused next AdaLN: x += g*(A@W); xa = ln(x)*lg+lb ---
template<int KT, bool FUSE>
__global__ __launch_bounds__(256) void resid_fused(const bf16* __restrict__ Ain,
    const bf16* __restrict__ Wt, const bf16* __restrict__ gsk,
    float* __restrict__ x,
    const bf16* __restrict__ lng, const bf16* __restrict__ lnb,
    bf16* __restrict__ xaout){
  __shared__ bf16 Bs[128*(KT*32+8)];
  int tid = threadIdx.x, wave = tid >> 6, lane = tid & 63;
  int l16 = lane & 15, quad = lane >> 4;
  int m0 = blockIdx.x*128;
  int mrow = m0 + wave*32;
  bf16x8 a0[KT], a1[KT];
  loadA2<KT>(Ain, mrow, l16, quad, a0, a1);
  stage_direct<KT>(Bs, Wt, tid);
  __syncthreads();
  f32x4 z = {0.f,0.f,0.f,0.f};
  f32x4 acc0[8], acc1[8];
  #pragma unroll
  for (int nt = 0; nt < 8; nt++){ acc0[nt] = z; acc1[nt] = z; }
  mma_blockT<KT>(Bs, a0, a1, acc0, acc1, l16, quad);
  #pragma unroll
  for (int s = 0; s < 2; s++){
    f32x4* acc = s ? acc1 : acc0;
    int mr = mrow + s*16 + quad*4;
    #pragma unroll
    for (int nt = 0; nt < 8; nt++)
    #pragma unroll
    for (int r = 0; r < 4; r++){
      size_t idx = (size_t)(mr + r)*CA + nt*16 + l16;
      float v = x[idx] + (float)gsk[idx]*acc[nt][r];
      x[idx] = v;
      acc[nt][r] = v;
    }
    if constexpr (FUSE){
      #pragma unroll
      for (int r = 0; r < 4; r++){
        float sm = 0.f;
        #pragma unroll
        for (int nt = 0; nt < 8; nt++) sm += acc[nt][r];
        #pragma unroll
        for (int off = 1; off < 16; off <<= 1) sm += __shfl_xor(sm, off);
        float mu = sm*(1.f/128.f);
        float vs = 0.f;
        #pragma unroll
        for (int nt = 0; nt < 8; nt++){
          float d = acc[nt][r] - mu; vs += d*d;
        }
        #pragma unroll
        for (int off = 1; off < 16; off <<= 1) vs += __shfl_xor(vs, off);
        float rs = rsqrtf(vs*(1.f/128.f) + 1e-5f);
        #pragma unroll
        for (int nt = 0; nt < 8; nt++){
          size_t idx = (size_t)(mr + r)*CA + nt*16 + l16;
          float xn = (acc[nt][r] - mu)*rs;
          xaout[idx] = (bf16)((float)lng[idx]*xn + (float)lnb[idx]);
        }
      }
    }
  }
}

// ---------------- SwiGLU first stage (two matrices, double-buffered) --------
__global__ __launch_bounds__(256) void t12_gemm(const bf16* __restrict__ xt,
    const bf16* __restrict__ Wt1, const bf16* __restrict__ Wt2,
    bf16* __restrict__ hsw){
  __shared__ bf16 Bs[2][128*136];
  int tid = threadIdx.x, wave = tid >> 6, lane = tid & 63;
  int l16 = lane & 15, quad = lane >> 4;
  int m0 = blockIdx.x*128;
  int n0 = blockIdx.y*128;
  int mrow = m0 + wave*32;
  bf16x8 a0[4], a1[4];
  loadA2<4>(xt, mrow, l16, quad, a0, a1);
  uint4 stg[8];
  stageB_load<4>(Wt1 + (size_t)n0*128, stg, tid);
  stageB_write<4>(Bs[0], stg, tid);
  __syncthreads();
  stageB_load<4>(Wt2 + (size_t)n0*128, stg, tid);
  f32x4 z = {0.f,0.f,0.f,0.f};
  f32x4 accA0[8], accA1[8], accB0[8], accB1[8];
  #pragma unroll
  for (int nt = 0; nt < 8; nt++){ accA0[nt] = z; accA1[nt] = z; accB0[nt] = z; accB1[nt] = z; }
  mma_blockT<4>(Bs[0], a0, a1, accA0, accA1, l16, quad);
  stageB_write<4>(Bs[1], stg, tid);
  __syncthreads();
  mma_blockT<4>(Bs[1], a0, a1, accB0, accB1, l16, quad);
  #pragma unroll
  for (int s = 0; s < 2; s++)
  #pragma unroll
  for (int nt = 0; nt < 8; nt++)
  #pragma unroll
  for (int r = 0; r < 4; r++){
    int m = mrow + s*16 + quad*4 + r;
    int n = n0 + nt*16 + l16;
    float v1 = (s ? accA1 : accA0)[nt][r];
    float v2 = (s ? accB1 : accB0)[nt][r];
    hsw[(size_t)m*(2*CA) + n] = (bf16)(v1*sigmoidf_(v1)*v2);
  }
}

// ---------------- final LN + projection to 3 ----------------
__global__ __launch_bounds__(256) void final_kernel(const float* __restrict__ x,
    const float* __restrict__ amask, const float* __restrict__ lg,
    const float* __restrict__ lb, const float* __restrict__ Wout,
    float* __restrict__ outp){
  int ga = blockIdx.x * 4 + (threadIdx.x >> 6);
  int lane = threadIdx.x & 63;
  float2 xv = *reinterpret_cast<const float2*>(x + (size_t)ga*CA + lane*2);
  float m = amask[ga];
  xv.x *= m; xv.y *= m;
  float s = red_sum64(xv.x + xv.y);
  float mu = s * (1.f/128.f);
  float d0 = xv.x - mu, d1 = xv.y - mu;
  float vs = red_sum64(d0*d0 + d1*d1);
  float rs = rsqrtf(vs*(1.f/128.f) + 1e-5f);
  int c = lane*2;
  float xn0 = d0*rs*lg[c]   + lb[c];
  float xn1 = d1*rs*lg[c+1] + lb[c+1];
  float p0 = xn0*Wout[c*3+0] + xn1*Wout[(c+1)*3+0];
  float p1 = xn0*Wout[c*3+1] + xn1*Wout[(c+1)*3+1];
  float p2 = xn0*Wout[c*3+2] + xn1*Wout[(c+1)*3+2];
  p0 = red_sum64(p0); p1 = red_sum64(p1); p2 = red_sum64(p2);
  if (lane == 0){
    outp[(size_t)ga*3 + 0] = p0;
    outp[(size_t)ga*3 + 1] = p1;
    outp[(size_t)ga*3 + 2] = p2;
  }
}

extern "C" void kernel_launch(void* const* d_in, const int* in_sizes, int n_in,
                              void* d_out, int out_size, void* d_ws, size_t ws_size,
                              hipStream_t stream){
  (void)in_sizes; (void)n_in; (void)out_size; (void)ws_size;
  const float* a     = (const float*)d_in[0];
  const float* ef    = (const float*)d_in[2];
  const float* p_lm  = (const float*)d_in[3];
  const float* amask = (const float*)d_in[4];
  const int*   a2t   = (const int*)d_in[5];
  const float* Wa    = (const float*)d_in[6];
  const float* lnq_g = (const float*)d_in[7];
  const float* lnq_b = (const float*)d_in[8];
  const float* Wout  = (const float*)d_in[9];
  const float* ag_w  = (const float*)d_in[10];
  const float* ag_b  = (const float*)d_in[11];
  const float* ab_w  = (const float*)d_in[12];
  const float* wq    = (const float*)d_in[13];
  const float* bq    = (const float*)d_in[14];
  const float* wk    = (const float*)d_in[15];
  const float* wv    = (const float*)d_in[16];
  const float* pg    = (const float*)d_in[17];
  const float* pb    = (const float*)d_in[18];
  const float* wpb   = (const float*)d_in[19];
  const float* wg    = (const float*)d_in[20];
  const float* wo    = (const float*)d_in[21];
  const float* sk_w  = (const float*)d_in[22];
  const float* sk_b  = (const float*)d_in[23];
  const float* tg_w  = (const float*)d_in[24];
  const float* tg_b  = (const float*)d_in[25];
  const float* tb_w  = (const float*)d_in[26];
  const float* wt1   = (const float*)d_in[27];
  const float* wt2   = (const float*)d_in[28];
  const float* wto   = (const float*)d_in[29];
  const float* tk_w  = (const float*)d_in[30];
  const float* tk_b  = (const float*)d_in[31];
  float* out = (float*)d_out;
  char* ws = (char*)d_ws;

  const size_t OFF_X    = 0;
  const size_t OFF_SNC  = OFF_X    + (size_t)MTOT*CA*4;
  const size_t OFF_TVAL = OFF_SNC  + (size_t)MTOT*CA*2;
  const size_t OFF_AW   = OFF_TVAL + (size_t)MTOT*4;
  const size_t OFF_CS   = OFF_AW   + (size_t)BB*NTOK*CA*4;
  const size_t OFF_WT   = OFF_CS   + 18*CA*4 + 256;
  const size_t OFF_COND = OFF_WT   + (size_t)WT_TOTAL*2 + 256;
  const size_t OFF_XA   = OFF_COND + (size_t)18*CSZ*2;
  const size_t OFF_QKVG = OFF_XA   + (size_t)MTOT*CA*2;
  const size_t OFF_HSW  = OFF_QKVG + (size_t)MTOT*512*2;
  const size_t OFF_GO   = OFF_HSW  + (size_t)MTOT*256*2;
  const size_t OFF_BIAS = OFF_GO   + (size_t)MTOT*CA*2;

  float* x    = (float*)(ws + OFF_X);
  bf16*  snc  = (bf16*)(ws + OFF_SNC);
  float* tval = (float*)(ws + OFF_TVAL);
  float* aW   = (float*)(ws + OFF_AW);
  float* cs   = (float*)(ws + OFF_CS);
  bf16*  wt   = (bf16*)(ws + OFF_WT);
  bf16*  cond = (bf16*)(ws + OFF_COND);
  bf16*  xa   = (bf16*)(ws + OFF_XA);
  bf16*  qkvg = (bf16*)(ws + OFF_QKVG);
  bf16*  hsw  = (bf16*)(ws + OFF_HSW);
  bf16*  go   = (bf16*)(ws + OFF_GO);
  bf16*  biasg= (bf16*)(ws + OFF_BIAS);

  token_gemm<<<BB*NTOK, 128, 0, stream>>>(a, Wa, aW);
  build_x0<<<MTOT/4, 256, 0, stream>>>(aW, ef, amask, a2t, x, snc, tval);
  wconv<<<96, 256, 0, stream>>>(ag_w, ab_w, sk_w, tg_w, tb_w, tk_w,
      wq, wk, wv, wg, wo, wt1, wt2, wto, wt);
  colsums<<<18, 128, 0, stream>>>(ag_w, ab_w, sk_w, tg_w, tb_w, tk_w, cs);
  cond_all<<<dim3(MTOT/128, 3), 256, 0, stream>>>(snc, tval, wt + WT_COND_OFF,
      ag_b, sk_b, tg_b, tk_b, cs, cond);
  bias_all<<<dim3(NWIN, BB), 256, 0, stream>>>(p_lm, pg, pb, wpb, biasg);
  adaln_kernel<<<MTOT/4, 256, 0, stream>>>(x, cond, cond + CSZ, xa);

  for (int i = 0; i < 3; i++){
    qkvg_gemm<<<MTOT/128, 256, 0, stream>>>(xa,
        wt + WT_QKVG_OFF + (size_t)i*4*16384, bq + (size_t)i*CA, qkvg);
    attn_kernel<<<dim3(NWIN, BB), 256, 0, stream>>>(qkvg,
        biasg + (size_t)i*BIAS_I, amask, go);
    resid_fused<4,true><<<MTOT/128, 256, 0, stream>>>(go,
        wt + WT_WO_OFF + (size_t)i*16384, cond + (size_t)(i*6+2)*CSZ, x,
        cond + (size_t)(i*6+3)*CSZ, cond + (size_t)(i*6+4)*CSZ, xa);
    t12_gemm<<<dim3(MTOT/128, 2), 256, 0, stream>>>(xa,
        wt + WT_T12_OFF + (size_t)(2*i)*32768,
        wt + WT_T12_OFF + (size_t)(2*i+1)*32768, hsw);
    if (i < 2)
      resid_fused<8,true><<<MTOT/128, 256, 0, stream>>>(hsw,
          wt + WT_WTO_OFF + (size_t)i*32768, cond + (size_t)(i*6+5)*CSZ, x,
          cond + (size_t)((i+1)*6+0)*CSZ, cond + (size_t)((i+1)*6+1)*CSZ, xa);
    else
      resid_fused<8,false><<<MTOT/128, 256, 0, stream>>>(hsw,
          wt + WT_WTO_OFF + (size_t)i*32768, cond + (size_t)(i*6+5)*CSZ, x,
          nullptr, nullptr, nullptr);
  }
  final_kernel<<<MTOT/4, 256, 0, stream>>>(x, amask, lnq_g, lnq_b, Wout, out);
}

// Round 4
// 901.900 us; speedup vs baseline: 1.4167x; 1.1472x over previous
//
#include <hip/hip_runtime.h>
#include <hip/hip_bf16.h>

typedef __bf16 bf16;
typedef __bf16 bf16x8 __attribute__((ext_vector_type(8)));
typedef float f32x4 __attribute__((ext_vector_type(4)));

#define DEV static __device__ __forceinline__

#define BB 2
#define NTOK 512
#define NATOM 16384
#define CT 384
#define CA 128
#define CP 16
#define CS 384
#define NQ 32
#define NK 128
#define NH 4
#define DH 32
#define NWIN 512
#define MTOT (BB*NATOM) /* 32768 */
#define CSZ ((size_t)MTOT*CA)

// transposed-bf16 weight arena offsets (elements)
#define WT_COND_OFF 0        /* 18 x [128][128] */
#define WT_QKVG_OFF 294912   /* 12 x [128][128] */
#define WT_WO_OFF   491520   /* 3 x [128][128]  */
#define WT_T12_OFF  540672   /* 6 x [256][128]  */
#define WT_WTO_OFF  737280   /* 3 x [128][256]  */
#define WT_TOTAL    835584
#define BIAS_I      16777216 /* bias elems per block-i: 2*512*4096*4 */

DEV bf16x8 lds_ld8(const bf16* p){
  union { uint2 u[2]; bf16x8 v; } t;
  t.u[0] = *reinterpret_cast<const uint2*>(p);
  t.u[1] = *reinterpret_cast<const uint2*>(p + 4);
  return t.v;
}
DEV bf16x8 lds_ld16(const bf16* p){
  union { uint4 u; bf16x8 v; } t;
  t.u = *reinterpret_cast<const uint4*>(p);
  return t.v;
}
DEV bf16x8 ldg8(const bf16* p){
  union { uint4 u; bf16x8 v; } t;
  t.u = *reinterpret_cast<const uint4*>(p);
  return t.v;
}
DEV f32x4 mfma16(bf16x8 a, bf16x8 b, f32x4 c){
  return __builtin_amdgcn_mfma_f32_16x16x32_bf16(a, b, c, 0, 0, 0);
}
DEV float sigmoidf_(float x){ return 1.f/(1.f + __expf(-x)); }
DEV float red_sum64(float v){
  #pragma unroll
  for (int off = 1; off < 64; off <<= 1) v += __shfl_xor(v, off);
  return v;
}

// ============ GEMM engine (operand-swapped) =================================
// W (bf16 [n][K], pre-transposed) staged to LDS, used as MFMA **A** operand.
// Activations read from global into regs, used as MFMA **B** operand.
// C/D layout: lane(quad,l16) holds C[n = nt*16+quad*4+r][m = mrow+s*16+l16]
// -> 4 consecutive output columns per lane => 8B/16B packed stores.

// stage ROWS x 128 bf16 slab (global row stride ldk) into LDS [ROWS][136]
template<int ROWS>
DEV void stageW128(bf16* __restrict__ Bs, const bf16* __restrict__ Bg,
                   int ldk, int tid){
  uint4 v[ROWS/16];
  #pragma unroll
  for (int i = 0; i < ROWS/16; i++){
    int c = tid + i*256;
    int row = c >> 4, ko = (c & 15)*8;
    v[i] = *reinterpret_cast<const uint4*>(Bg + (size_t)row*ldk + ko);
  }
  #pragma unroll
  for (int i = 0; i < ROWS/16; i++){
    int c = tid + i*256;
    int row = c >> 4, ko = (c & 15)*8;
    *reinterpret_cast<uint4*>(Bs + row*136 + ko) = v[i];
  }
}
// activation fragments (B-operand): 2 row-slabs of 16, k in [k0, k0+128)
DEV void loadA2(const bf16* __restrict__ A, int row0, int ldk, int k0,
                int l16, int quad, bf16x8* b0, bf16x8* b1){
  const bf16* r0 = A + (size_t)(row0 + l16)*ldk + k0 + quad*8;
  const bf16* r1 = r0 + (size_t)16*ldk;
  #pragma unroll
  for (int ks = 0; ks < 4; ks++){
    b0[ks] = ldg8(r0 + ks*32);
    b1[ks] = ldg8(r1 + ks*32);
  }
}
template<int NT>
DEV void mma_swp(const bf16* Bs, const bf16x8* b0, const bf16x8* b1,
                 f32x4* acc0, f32x4* acc1, int l16, int quad){
  #pragma unroll
  for (int nt = 0; nt < NT; nt++){
    const bf16* wp = Bs + (nt*16 + l16)*136 + quad*8;
    #pragma unroll
    for (int ks = 0; ks < 4; ks++){
      bf16x8 w = lds_ld16(wp + ks*32);
      acc0[nt] = mfma16(w, b0[ks], acc0[nt]);
      acc1[nt] = mfma16(w, b1[ks], acc1[nt]);
    }
  }
}
DEV f32x4 bf4_to_f4(uint2 u){
  union { uint2 uu; bf16 h[4]; } t; t.uu = u;
  f32x4 r = { (float)t.h[0], (float)t.h[1], (float)t.h[2], (float)t.h[3] };
  return r;
}
DEV uint2 f4_to_bf4(f32x4 v){
  union { uint2 uu; bf16 h[4]; } t;
  t.h[0] = (bf16)v.x; t.h[1] = (bf16)v.y; t.h[2] = (bf16)v.z; t.h[3] = (bf16)v.w;
  return t.uu;
}

// ---------------- weight prep: f32 [K][N] -> bf16 [N][K] ----------------
__global__ __launch_bounds__(256) void wconv(
    const float* ag, const float* ab, const float* sk,
    const float* tg, const float* tb, const float* tk,
    const float* wq, const float* wk, const float* wv, const float* wg,
    const float* wo, const float* wt1, const float* wt2, const float* wto,
    bf16* __restrict__ wt){
  __shared__ __align__(16) bf16 T[64][264];
  int s = blockIdx.x;
  int mat, nslab;
  if (s < 66){ mat = s >> 1; nslab = s & 1; }
  else if (s < 90){ mat = 33 + (s-66)/4; nslab = (s-66)&3; }
  else { mat = 39 + ((s-90)>>1); nslab = (s-90)&1; }
  const float* src; int K, N; size_t dst;
  if (mat < 18){ int i = mat/6, t = mat - i*6;
    const float* base = t==0?ag:t==1?ab:t==2?sk:t==3?tg:t==4?tb:tk;
    src = base + (size_t)i*CS*CA; K=128; N=128; dst = WT_COND_OFF + (size_t)mat*16384; }
  else if (mat < 30){ int q = mat-18; int i=q>>2, sx=q&3;
    const float* base = sx==0?wq:sx==1?wk:sx==2?wv:wg;
    src = base + (size_t)i*16384; K=128; N=128; dst = WT_QKVG_OFF + (size_t)q*16384; }
  else if (mat < 33){ src = wo + (size_t)(mat-30)*16384; K=128; N=128;
    dst = WT_WO_OFF + (size_t)(mat-30)*16384; }
  else if (mat < 39){ int q = mat-33; int i=q>>1, sx=q&1;
    src = (sx? wt2 : wt1) + (size_t)i*32768; K=128; N=256;
    dst = WT_T12_OFF + (size_t)q*32768; }
  else { src = wto + (size_t)(mat-39)*32768; K=256; N=128;
    dst = WT_WTO_OFF + (size_t)(mat-39)*32768; }
  int n0 = nslab*64;
  int tid = threadIdx.x;
  for (int c = tid; c < K*16; c += 256){
    int k = c >> 4, nq = c & 15;
    float4 v = *reinterpret_cast<const float4*>(src + (size_t)k*N + n0 + nq*4);
    T[nq*4+0][k] = (bf16)v.x; T[nq*4+1][k] = (bf16)v.y;
    T[nq*4+2][k] = (bf16)v.z; T[nq*4+3][k] = (bf16)v.w;
  }
  __syncthreads();
  int KQ = K >> 3;
  for (int c = tid; c < 64*KQ; c += 256){
    int n = c / KQ, kq = c - n*KQ;
    uint4 d = *reinterpret_cast<const uint4*>(&T[n][kq*8]);
    *reinterpret_cast<uint4*>(wt + dst + (size_t)(n0+n)*K + kq*8) = d;
  }
}

// ---------------- small prologue kernels ----------------
__global__ __launch_bounds__(128) void token_gemm(const float* __restrict__ a,
    const float* __restrict__ Wa, float* __restrict__ aW){
  __shared__ float arow[CT];
  int row = blockIdx.x;
  for (int j = threadIdx.x; j < CT; j += 128) arow[j] = a[(size_t)row*CT + j];
  __syncthreads();
  int c = threadIdx.x;
  float s = 0.f;
  for (int j = 0; j < CT; j++) s += arow[j] * Wa[(size_t)j*CA + c];
  aW[(size_t)row*CA + c] = s;
}

__global__ __launch_bounds__(256) void build_x0(const float* __restrict__ aW,
    const float* __restrict__ ef, const float* __restrict__ amask,
    const int* __restrict__ a2t, float* __restrict__ x,
    bf16* __restrict__ snc, float* __restrict__ tval){
  int ga = blockIdx.x * 4 + (threadIdx.x >> 6);
  int lane = threadIdx.x & 63;
  int b = ga >> 14;
  int tok = a2t[ga];
  float2 av = *reinterpret_cast<const float2*>(aW + ((size_t)(b*NTOK + tok))*CA + lane*2);
  float2 ev = *reinterpret_cast<const float2*>(ef + (size_t)ga*CA + lane*2);
  float m = amask[ga];
  *reinterpret_cast<float2*>(x + (size_t)ga*CA + lane*2) =
      make_float2((av.x + ev.x)*m, (av.y + ev.y)*m);
  float s = red_sum64(ev.x + ev.y);
  float mu = s * (1.f/384.f);
  float d0 = ev.x - mu, d1 = ev.y - mu;
  float vs = red_sum64(d0*d0 + d1*d1);
  float var = (vs + 256.f*mu*mu) * (1.f/384.f);
  float rs = rsqrtf(var + 1e-5f);
  bf16* sp = snc + (size_t)ga*CA + lane*2;
  sp[0] = (bf16)(d0*rs); sp[1] = (bf16)(d1*rs);
  if (lane == 0) tval[ga] = -mu*rs;
}

__global__ __launch_bounds__(128) void colsums(const float* ag, const float* ab,
    const float* sk, const float* tg, const float* tb, const float* tk,
    float* __restrict__ cs){
  int mat = blockIdx.x;              // 0..17 = i*6+t
  int i = mat / 6, t = mat % 6;
  const float* base = t==0?ag : t==1?ab : t==2?sk : t==3?tg : t==4?tb : tk;
  const float* W = base + (size_t)i*CS*CA;
  int c = threadIdx.x;
  float s = 0.f;
  for (int k = CA; k < CS; k++) s += W[(size_t)k*CA + c];
  cs[(size_t)mat*CA + c] = s;
}

// ------------- conditioning GEMMs: one matrix per block, swapped ------------
__global__ __launch_bounds__(256) void cond_all(const bf16* __restrict__ snc,
    const float* __restrict__ tval, const bf16* __restrict__ wtc,
    const float* __restrict__ ag_b, const float* __restrict__ sk_b,
    const float* __restrict__ tg_b, const float* __restrict__ tk_b,
    const float* __restrict__ cs, bf16* __restrict__ cond){
  __shared__ bf16 Bs[128*136];
  int tid = threadIdx.x, wave = tid >> 6, lane = tid & 63;
  int l16 = lane & 15, quad = lane >> 4;
  int mat = blockIdx.x;              // i*6+t  (fastest dim -> A-tile shared in L2)
  int i = mat/6, t = mat - i*6;
  int m0 = blockIdx.y*128;
  int mrow = m0 + wave*32;
  bf16x8 b0[4], b1[4];
  loadA2(snc, mrow, CA, 0, l16, quad, b0, b1);
  stageW128<128>(Bs, wtc + (size_t)mat*16384, 128, tid);
  __syncthreads();
  f32x4 z = {0.f,0.f,0.f,0.f};
  f32x4 acc0[8], acc1[8];
  #pragma unroll
  for (int nt = 0; nt < 8; nt++){ acc0[nt] = z; acc1[nt] = z; }
  mma_swp<8>(Bs, b0, b1, acc0, acc1, l16, quad);
  const float* csr = cs + (size_t)mat*CA;
  const float* bias = t==0 ? ag_b + (size_t)i*CA : t==2 ? sk_b + (size_t)i*CA
                    : t==3 ? tg_b + (size_t)i*CA : t==5 ? tk_b + (size_t)i*CA : nullptr;
  bool sig = (t==0)||(t==2)||(t==3)||(t==5);
  bf16* op = cond + (size_t)mat*CSZ;
  #pragma unroll
  for (int s = 0; s < 2; s++){
    int m = mrow + s*16 + l16;
    float tv = tval[m];
    f32x4* acc = s ? acc1 : acc0;
    #pragma unroll
    for (int nt = 0; nt < 8; nt++){
      int nb = nt*16 + quad*4;
      f32x4 v = acc[nt] + tv * (*reinterpret_cast<const f32x4*>(csr + nb));
      if (bias) v += *reinterpret_cast<const f32x4*>(bias + nb);
      if (sig){
        v.x = sigmoidf_(v.x); v.y = sigmoidf_(v.y);
        v.z = sigmoidf_(v.z); v.w = sigmoidf_(v.w);
      }
      *reinterpret_cast<uint2*>(op + (size_t)m*CA + nb) = f4_to_bf4(v);
    }
  }
}

// ---------------- pair bias for all 3 blocks, SINGLE p_lm pass ----------------
__global__ __launch_bounds__(256) void bias_all(const float* __restrict__ p_lm,
    const float* __restrict__ pg, const float* __restrict__ pb,
    const float* __restrict__ wpb, bf16* __restrict__ biasg){
  __shared__ f32x4 wjS[3][16];
  __shared__ f32x4 wsumS[3], ccS[3];
  int w = blockIdx.x, b = blockIdx.y;
  int tid = threadIdx.x;
  if (tid < 48){
    int i = tid >> 4, j = tid & 15;
    f32x4 wp = *reinterpret_cast<const f32x4*>(wpb + (size_t)(i*16+j)*4);
    wjS[i][j] = pg[i*16+j]*wp;
  }
  __syncthreads();
  if (tid < 3){
    f32x4 s = {0.f,0.f,0.f,0.f}, c = {0.f,0.f,0.f,0.f};
    for (int j = 0; j < 16; j++){
      s += wjS[tid][j];
      f32x4 wp = *reinterpret_cast<const f32x4*>(wpb + (size_t)(tid*16+j)*4);
      c += pb[tid*16+j]*wp;
    }
    wsumS[tid] = s; ccS[tid] = c;
  }
  __syncthreads();
  size_t pbase = (size_t)(b*NWIN + w)*(NQ*NK*CP);
  size_t obase = (size_t)(b*NWIN + w)*4096*4;
  #pragma unroll 1
  for (int t = 0; t < 16; t++){
    int pid = t*256 + tid;
    const float* pp = p_lm + pbase + (size_t)pid*16;
    float4 p0 = *reinterpret_cast<const float4*>(pp);
    float4 p1 = *reinterpret_cast<const float4*>(pp + 4);
    float4 p2 = *reinterpret_cast<const float4*>(pp + 8);
    float4 p3 = *reinterpret_cast<const float4*>(pp + 12);
    float sm = p0.x+p0.y+p0.z+p0.w + p1.x+p1.y+p1.z+p1.w
             + p2.x+p2.y+p2.z+p2.w + p3.x+p3.y+p3.z+p3.w;
    float sq = p0.x*p0.x+p0.y*p0.y+p0.z*p0.z+p0.w*p0.w
             + p1.x*p1.x+p1.y*p1.y+p1.z*p1.z+p1.w*p1.w
             + p2.x*p2.x+p2.y*p2.y+p2.z*p2.z+p2.w*p2.w
             + p3.x*p3.x+p3.y*p3.y+p3.z*p3.z+p3.w*p3.w;
    float mu = sm * (1.f/16.f);
    float var = fmaxf(sq*(1.f/16.f) - mu*mu, 0.f);
    float rsg = rsqrtf(var + 1e-5f);
    #pragma unroll
    for (int i = 0; i < 3; i++){
      f32x4 dw = {0.f,0.f,0.f,0.f};
      dw += p0.x*wjS[i][0];  dw += p0.y*wjS[i][1];  dw += p0.z*wjS[i][2];  dw += p0.w*wjS[i][3];
      dw += p1.x*wjS[i][4];  dw += p1.y*wjS[i][5];  dw += p1.z*wjS[i][6];  dw += p1.w*wjS[i][7];
      dw += p2.x*wjS[i][8];  dw += p2.y*wjS[i][9];  dw += p2.z*wjS[i][10]; dw += p2.w*wjS[i][11];
      dw += p3.x*wjS[i][12]; dw += p3.y*wjS[i][13]; dw += p3.z*wjS[i][14]; dw += p3.w*wjS[i][15];
      f32x4 b4 = rsg*(dw - mu*wsumS[i]) + ccS[i];
      *reinterpret_cast<uint2*>(biasg + (size_t)i*BIAS_I + obase + (size_t)pid*4) = f4_to_bf4(b4);
    }
  }
}

// ---------------- AdaLN (standalone, used once for block 0) ----------------
__global__ __launch_bounds__(256) void adaln_kernel(const float* __restrict__ x,
    const bf16* __restrict__ g, const bf16* __restrict__ bt, bf16* __restrict__ outp){
  int ga = blockIdx.x * 4 + (threadIdx.x >> 6);
  int lane = threadIdx.x & 63;
  float2 xv = *reinterpret_cast<const float2*>(x + (size_t)ga*CA + lane*2);
  float s = red_sum64(xv.x + xv.y);
  float mu = s * (1.f/128.f);
  float d0 = xv.x - mu, d1 = xv.y - mu;
  float vs = red_sum64(d0*d0 + d1*d1);
  float rs = rsqrtf(vs*(1.f/128.f) + 1e-5f);
  const bf16* gp = g  + (size_t)ga*CA + lane*2;
  const bf16* bp = bt + (size_t)ga*CA + lane*2;
  bf16* op = outp + (size_t)ga*CA + lane*2;
  op[0] = (bf16)((float)gp[0]*(d0*rs) + (float)bp[0]);
  op[1] = (bf16)((float)gp[1]*(d1*rs) + (float)bp[1]);
}

// ---------------- QKVG projections: one matrix per block, swapped -----------
__global__ __launch_bounds__(256) void qkvg_gemm(const bf16* __restrict__ xa,
    const bf16* __restrict__ wt, const float* __restrict__ bq,
    bf16* __restrict__ outq){
  __shared__ bf16 Bs[128*136];
  int tid = threadIdx.x, wave = tid >> 6, lane = tid & 63;
  int l16 = lane & 15, quad = lane >> 4;
  int sel = blockIdx.x;
  int m0 = blockIdx.y*128;
  int mrow = m0 + wave*32;
  bf16x8 b0[4], b1[4];
  loadA2(xa, mrow, CA, 0, l16, quad, b0, b1);
  stageW128<128>(Bs, wt + (size_t)sel*16384, 128, tid);
  __syncthreads();
  f32x4 z = {0.f,0.f,0.f,0.f};
  f32x4 acc0[8], acc1[8];
  #pragma unroll
  for (int nt = 0; nt < 8; nt++){ acc0[nt] = z; acc1[nt] = z; }
  mma_swp<8>(Bs, b0, b1, acc0, acc1, l16, quad);
  const float invs = 0.17677669529663689f;
  #pragma unroll
  for (int s = 0; s < 2; s++){
    int m = mrow + s*16 + l16;
    f32x4* acc = s ? acc1 : acc0;
    #pragma unroll
    for (int nt = 0; nt < 8; nt++){
      int nb = nt*16 + quad*4;
      f32x4 v = acc[nt];
      if (sel == 0)
        v = (v + *reinterpret_cast<const f32x4*>(bq + nb)) * invs;
      if (sel == 3){
        v.x = sigmoidf_(v.x); v.y = sigmoidf_(v.y);
        v.z = sigmoidf_(v.z); v.w = sigmoidf_(v.w);
      }
      *reinterpret_cast<uint2*>(outq + (size_t)m*512 + sel*128 + nb) = f4_to_bf4(v);
    }
  }
}

// ---------------- windowed attention (bias precomputed) ----------------
__global__ __launch_bounds__(256) void attn_kernel(const bf16* __restrict__ qkvg,
    const bf16* __restrict__ biasg, const float* __restrict__ amask,
    bf16* __restrict__ go){
  __shared__ bf16 Qs[32][136];
  __shared__ bf16 Ks[128][136];   // reused as P buffers
  __shared__ bf16 Vts[128][136];  // V transposed [d][key]
  __shared__ float kmask[128];
  int w = blockIdx.x, b = blockIdx.y;
  int tid = threadIdx.x;
  int wave = tid >> 6, lane = tid & 63, l16 = lane & 15, quad = lane >> 4;
  size_t abase = (size_t)b*NATOM + (size_t)w*NQ;
  int kstart = w*NQ + NQ/2 - NK/2;
  if (tid < 128){
    int pos = kstart + tid;
    kmask[tid] = (pos >= 0 && pos < NATOM) ? amask[(size_t)b*NATOM + pos] : 0.f;
  }
  #pragma unroll
  for (int i = 0; i < 2; i++){
    int c = tid + i*256;
    int row = c >> 4, off = (c & 15)*8;
    uint4 d = *reinterpret_cast<const uint4*>(qkvg + (abase + row)*512 + off);
    *reinterpret_cast<uint4*>(&Qs[row][off]) = d;
  }
  #pragma unroll
  for (int i = 0; i < 8; i++){
    int c = tid + i*256;
    int row = c >> 4, off = (c & 15)*8;
    int ka = kstart + row; ka = ka < 0 ? 0 : (ka > NATOM-1 ? NATOM-1 : ka);
    uint4 d = *reinterpret_cast<const uint4*>(qkvg + ((size_t)b*NATOM + ka)*512 + 128 + off);
    *reinterpret_cast<uint4*>(&Ks[row][off]) = d;
  }
  #pragma unroll
  for (int i = 0; i < 16; i++){
    int c = tid + i*256;
    int row = c >> 5, off = (c & 31)*4;
    int ka = kstart + row; ka = ka < 0 ? 0 : (ka > NATOM-1 ? NATOM-1 : ka);
    uint2 d = *reinterpret_cast<const uint2*>(qkvg + ((size_t)b*NATOM + ka)*512 + 256 + off);
    union { uint2 u; bf16 h[4]; } t; t.u = d;
    Vts[off+0][row] = t.h[0];
    Vts[off+1][row] = t.h[1];
    Vts[off+2][row] = t.h[2];
    Vts[off+3][row] = t.h[3];
  }
  __syncthreads();
  int h = wave;
  f32x4 z4 = {0.f,0.f,0.f,0.f};
  f32x4 sacc[2][8];
  #pragma unroll
  for (int mt = 0; mt < 2; mt++)
    #pragma unroll
    for (int nt = 0; nt < 8; nt++) sacc[mt][nt] = z4;
  {
    bf16x8 bfr[8];
    #pragma unroll
    for (int nt = 0; nt < 8; nt++) bfr[nt] = lds_ld8(&Ks[nt*16 + l16][h*32 + quad*8]);
    #pragma unroll
    for (int mt = 0; mt < 2; mt++){
      bf16x8 a = lds_ld8(&Qs[mt*16 + l16][h*32 + quad*8]);
      #pragma unroll
      for (int nt = 0; nt < 8; nt++) sacc[mt][nt] = mfma16(a, bfr[nt], sacc[mt][nt]);
    }
  }
  const bf16* bp = biasg + ((size_t)(b*NWIN + w)*4096)*4;
  #pragma unroll
  for (int mt = 0; mt < 2; mt++)
  #pragma unroll
  for (int r = 0; r < 4; r++){
    int q = mt*16 + quad*4 + r;
    #pragma unroll
    for (int nt = 0; nt < 8; nt++){
      int k = nt*16 + l16;
      float biasv = (float)bp[((size_t)q*128 + k)*4 + h];
      float sv = sacc[mt][nt][r] + biasv;
      sacc[mt][nt][r] = (kmask[k] > 0.f) ? sv : -1e9f;
    }
  }
  float rinv[2][4];
  #pragma unroll
  for (int mt = 0; mt < 2; mt++)
  #pragma unroll
  for (int r = 0; r < 4; r++){
    float mx = -3.0e38f;
    #pragma unroll
    for (int nt = 0; nt < 8; nt++) mx = fmaxf(mx, sacc[mt][nt][r]);
    #pragma unroll
    for (int off = 1; off < 16; off <<= 1) mx = fmaxf(mx, __shfl_xor(mx, off));
    float ss = 0.f;
    #pragma unroll
    for (int nt = 0; nt < 8; nt++){
      float e = __expf(sacc[mt][nt][r] - mx);
      sacc[mt][nt][r] = e; ss += e;
    }
    #pragma unroll
    for (int off = 1; off < 16; off <<= 1) ss += __shfl_xor(ss, off);
    rinv[mt][r] = 1.f/ss;
  }
  __syncthreads();   // all waves done with Ks (QK reads) -> reuse as P
  bf16 (*Ph)[136] = reinterpret_cast<bf16(*)[136]>(&Ks[h*32][0]);
  #pragma unroll
  for (int mt = 0; mt < 2; mt++)
  #pragma unroll
  for (int nt = 0; nt < 8; nt++)
  #pragma unroll
  for (int r = 0; r < 4; r++)
    Ph[mt*16 + quad*4 + r][nt*16 + l16] = (bf16)(sacc[mt][nt][r]*rinv[mt][r]);
  f32x4 oacc[2][2] = {{z4,z4},{z4,z4}};
  #pragma unroll
  for (int kt = 0; kt < 4; kt++){
    bf16x8 a0 = lds_ld8(&Ph[l16][kt*32 + quad*8]);
    bf16x8 a1 = lds_ld8(&Ph[16 + l16][kt*32 + quad*8]);
    bf16x8 b0 = lds_ld8(&Vts[h*32 + l16][kt*32 + quad*8]);
    bf16x8 b1 = lds_ld8(&Vts[h*32 + 16 + l16][kt*32 + quad*8]);
    oacc[0][0] = mfma16(a0, b0, oacc[0][0]);
    oacc[0][1] = mfma16(a0, b1, oacc[0][1]);
    oacc[1][0] = mfma16(a1, b0, oacc[1][0]);
    oacc[1][1] = mfma16(a1, b1, oacc[1][1]);
  }
  #pragma unroll
  for (int mt = 0; mt < 2; mt++)
  #pragma unroll
  for (int nt = 0; nt < 2; nt++)
  #pragma unroll
  for (int r = 0; r < 4; r++){
    int q = mt*16 + quad*4 + r;
    int dcol = h*32 + nt*16 + l16;
    size_t arow = abase + q;
    float gate = (float)qkvg[arow*512 + 384 + dcol];
    go[arow*CA + dcol] = (bf16)(gate * oacc[mt][nt][r]);
  }
}

// -------- residual GEMM + fused next AdaLN (operand-swapped) ----------------
template<int K, bool FUSE>
__global__ __launch_bounds__(256) void resid_fused(const bf16* __restrict__ Ain,
    const bf16* __restrict__ Wt, const bf16* __restrict__ gsk,
    float* __restrict__ x,
    const bf16* __restrict__ lng, const bf16* __restrict__ lnb,
    bf16* __restrict__ xaout){
  __shared__ bf16 Bs[128*136];
  int tid = threadIdx.x, wave = tid >> 6, lane = tid & 63;
  int l16 = lane & 15, quad = lane >> 4;
  int m0 = blockIdx.x*128;
  int mrow = m0 + wave*32;
  f32x4 z = {0.f,0.f,0.f,0.f};
  f32x4 acc0[8], acc1[8];
  #pragma unroll
  for (int nt = 0; nt < 8; nt++){ acc0[nt] = z; acc1[nt] = z; }
  #pragma unroll
  for (int kh = 0; kh < K/128; kh++){
    bf16x8 b0[4], b1[4];
    loadA2(Ain, mrow, K, kh*128, l16, quad, b0, b1);
    if (kh) __syncthreads();
    stageW128<128>(Bs, Wt + kh*128, K, tid);
    __syncthreads();
    mma_swp<8>(Bs, b0, b1, acc0, acc1, l16, quad);
  }
  #pragma unroll
  for (int s = 0; s < 2; s++){
    int m = mrow + s*16 + l16;
    f32x4* acc = s ? acc1 : acc0;
    float rowsum = 0.f;
    #pragma unroll
    for (int nt = 0; nt < 8; nt++){
      size_t idx = (size_t)m*CA + nt*16 + quad*4;
      f32x4 xv = *reinterpret_cast<const f32x4*>(x + idx);
      f32x4 g4 = bf4_to_f4(*reinterpret_cast<const uint2*>(gsk + idx));
      f32x4 v = xv + g4*acc[nt];
      *reinterpret_cast<f32x4*>(x + idx) = v;
      acc[nt] = v;
      rowsum += v.x + v.y + v.z + v.w;
    }
    if constexpr (FUSE){
      rowsum += __shfl_xor(rowsum, 16);
      rowsum += __shfl_xor(rowsum, 32);
      float mu = rowsum*(1.f/128.f);
      float vs = 0.f;
      #pragma unroll
      for (int nt = 0; nt < 8; nt++){
        f32x4 d = acc[nt] - mu;
        vs += d.x*d.x + d.y*d.y + d.z*d.z + d.w*d.w;
      }
      vs += __shfl_xor(vs, 16);
      vs += __shfl_xor(vs, 32);
      float rs = rsqrtf(vs*(1.f/128.f) + 1e-5f);
      #pragma unroll
      for (int nt = 0; nt < 8; nt++){
        size_t idx = (size_t)m*CA + nt*16 + quad*4;
        f32x4 g4 = bf4_to_f4(*reinterpret_cast<const uint2*>(lng + idx));
        f32x4 b4 = bf4_to_f4(*reinterpret_cast<const uint2*>(lnb + idx));
        f32x4 xn = (acc[nt] - mu)*rs;
        *reinterpret_cast<uint2*>(xaout + idx) = f4_to_bf4(g4*xn + b4);
      }
    }
  }
}

// ------- SwiGLU first stage: both W1/W2 n-halves staged, swapped ------------
__global__ __launch_bounds__(256) void t12_gemm(const bf16* __restrict__ xt,
    const bf16* __restrict__ Wt1, const bf16* __restrict__ Wt2,
    bf16* __restrict__ hsw){
  __shared__ bf16 Bs[128*136];
  int tid = threadIdx.x, wave = tid >> 6, lane = tid & 63;
  int l16 = lane & 15, quad = lane >> 4;
  int nh = blockIdx.x;               // n-half 0/1 (fastest -> A shared in L2)
  int m0 = blockIdx.y*128;
  int mrow = m0 + wave*32;
  bf16x8 b0[4], b1[4];
  loadA2(xt, mrow, CA, 0, l16, quad, b0, b1);
  stageW128<64>(Bs,          Wt1 + (size_t)nh*64*128, 128, tid);
  stageW128<64>(Bs + 64*136, Wt2 + (size_t)nh*64*128, 128, tid);
  __syncthreads();
  f32x4 z = {0.f,0.f,0.f,0.f};
  f32x4 accA0[4], accA1[4], accB0[4], accB1[4];
  #pragma unroll
  for (int nt = 0; nt < 4; nt++){ accA0[nt]=z; accA1[nt]=z; accB0[nt]=z; accB1[nt]=z; }
  mma_swp<4>(Bs,          b0, b1, accA0, accA1, l16, quad);
  mma_swp<4>(Bs + 64*136, b0, b1, accB0, accB1, l16, quad);
  #pragma unroll
  for (int s = 0; s < 2; s++){
    int m = mrow + s*16 + l16;
    #pragma unroll
    for (int nt = 0; nt < 4; nt++){
      int nb = nh*64 + nt*16 + quad*4;
      f32x4 v1 = (s ? accA1 : accA0)[nt];
      f32x4 v2 = (s ? accB1 : accB0)[nt];
      f32x4 o;
      o.x = v1.x*sigmoidf_(v1.x)*v2.x;
      o.y = v1.y*sigmoidf_(v1.y)*v2.y;
      o.z = v1.z*sigmoidf_(v1.z)*v2.z;
      o.w = v1.w*sigmoidf_(v1.w)*v2.w;
      *reinterpret_cast<uint2*>(hsw + (size_t)m*(2*CA) + nb) = f4_to_bf4(o);
    }
  }
}

// ---------------- final LN + projection to 3 ----------------
__global__ __launch_bounds__(256) void final_kernel(const float* __restrict__ x,
    const float* __restrict__ amask, const float* __restrict__ lg,
    const float* __restrict__ lb, const float* __restrict__ Wout,
    float* __restrict__ outp){
  int ga = blockIdx.x * 4 + (threadIdx.x >> 6);
  int lane = threadIdx.x & 63;
  float2 xv = *reinterpret_cast<const float2*>(x + (size_t)ga*CA + lane*2);
  float m = amask[ga];
  xv.x *= m; xv.y *= m;
  float s = red_sum64(xv.x + xv.y);
  float mu = s * (1.f/128.f);
  float d0 = xv.x - mu, d1 = xv.y - mu;
  float vs = red_sum64(d0*d0 + d1*d1);
  float rs = rsqrtf(vs*(1.f/128.f) + 1e-5f);
  int c = lane*2;
  float xn0 = d0*rs*lg[c]   + lb[c];
  float xn1 = d1*rs*lg[c+1] + lb[c+1];
  float p0 = xn0*Wout[c*3+0] + xn1*Wout[(c+1)*3+0];
  float p1 = xn0*Wout[c*3+1] + xn1*Wout[(c+1)*3+1];
  float p2 = xn0*Wout[c*3+2] + xn1*Wout[(c+1)*3+2];
  p0 = red_sum64(p0); p1 = red_sum64(p1); p2 = red_sum64(p2);
  if (lane == 0){
    outp[(size_t)ga*3 + 0] = p0;
    outp[(size_t)ga*3 + 1] = p1;
    outp[(size_t)ga*3 + 2] = p2;
  }
}

extern "C" void kernel_launch(void* const* d_in, const int* in_sizes, int n_in,
                              void* d_out, int out_size, void* d_ws, size_t ws_size,
                              hipStream_t stream){
  (void)in_sizes; (void)n_in; (void)out_size; (void)ws_size;
  const float* a     = (const float*)d_in[0];
  const float* ef    = (const float*)d_in[2];
  const float* p_lm  = (const float*)d_in[3];
  const float* amask = (const float*)d_in[4];
  const int*   a2t   = (const int*)d_in[5];
  const float* Wa    = (const float*)d_in[6];
  const float* lnq_g = (const float*)d_in[7];
  const float* lnq_b = (const float*)d_in[8];
  const float* Wout  = (const float*)d_in[9];
  const float* ag_w  = (const float*)d_in[10];
  const float* ag_b  = (const float*)d_in[11];
  const float* ab_w  = (const float*)d_in[12];
  const float* wq    = (const float*)d_in[13];
  const float* bq    = (const float*)d_in[14];
  const float* wk    = (const float*)d_in[15];
  const float* wv    = (const float*)d_in[16];
  const float* pg    = (const float*)d_in[17];
  const float* pb    = (const float*)d_in[18];
  const float* wpb   = (const float*)d_in[19];
  const float* wg    = (const float*)d_in[20];
  const float* wo    = (const float*)d_in[21];
  const float* sk_w  = (const float*)d_in[22];
  const float* sk_b  = (const float*)d_in[23];
  const float* tg_w  = (const float*)d_in[24];
  const float* tg_b  = (const float*)d_in[25];
  const float* tb_w  = (const float*)d_in[26];
  const float* wt1   = (const float*)d_in[27];
  const float* wt2   = (const float*)d_in[28];
  const float* wto   = (const float*)d_in[29];
  const float* tk_w  = (const float*)d_in[30];
  const float* tk_b  = (const float*)d_in[31];
  float* out = (float*)d_out;
  char* ws = (char*)d_ws;

  const size_t OFF_X    = 0;
  const size_t OFF_SNC  = OFF_X    + (size_t)MTOT*CA*4;
  const size_t OFF_TVAL = OFF_SNC  + (size_t)MTOT*CA*2;
  const size_t OFF_AW   = OFF_TVAL + (size_t)MTOT*4;
  const size_t OFF_CS   = OFF_AW   + (size_t)BB*NTOK*CA*4;
  const size_t OFF_WT   = OFF_CS   + 18*CA*4 + 256;
  const size_t OFF_COND = OFF_WT   + (size_t)WT_TOTAL*2 + 256;
  const size_t OFF_XA   = OFF_COND + (size_t)18*CSZ*2;
  const size_t OFF_QKVG = OFF_XA   + (size_t)MTOT*CA*2;
  const size_t OFF_HSW  = OFF_QKVG + (size_t)MTOT*512*2;
  const size_t OFF_GO   = OFF_HSW  + (size_t)MTOT*256*2;
  const size_t OFF_BIAS = OFF_GO   + (size_t)MTOT*CA*2;

  float* x    = (float*)(ws + OFF_X);
  bf16*  snc  = (bf16*)(ws + OFF_SNC);
  float* tval = (float*)(ws + OFF_TVAL);
  float* aW   = (float*)(ws + OFF_AW);
  float* cs   = (float*)(ws + OFF_CS);
  bf16*  wt   = (bf16*)(ws + OFF_WT);
  bf16*  cond = (bf16*)(ws + OFF_COND);
  bf16*  xa   = (bf16*)(ws + OFF_XA);
  bf16*  qkvg = (bf16*)(ws + OFF_QKVG);
  bf16*  hsw  = (bf16*)(ws + OFF_HSW);
  bf16*  go   = (bf16*)(ws + OFF_GO);
  bf16*  biasg= (bf16*)(ws + OFF_BIAS);

  token_gemm<<<BB*NTOK, 128, 0, stream>>>(a, Wa, aW);
  build_x0<<<MTOT/4, 256, 0, stream>>>(aW, ef, amask, a2t, x, snc, tval);
  wconv<<<96, 256, 0, stream>>>(ag_w, ab_w, sk_w, tg_w, tb_w, tk_w,
      wq, wk, wv, wg, wo, wt1, wt2, wto, wt);
  colsums<<<18, 128, 0, stream>>>(ag_w, ab_w, sk_w, tg_w, tb_w, tk_w, cs);
  cond_all<<<dim3(18, MTOT/128), 256, 0, stream>>>(snc, tval, wt + WT_COND_OFF,
      ag_b, sk_b, tg_b, tk_b, cs, cond);
  bias_all<<<dim3(NWIN, BB), 256, 0, stream>>>(p_lm, pg, pb, wpb, biasg);
  adaln_kernel<<<MTOT/4, 256, 0, stream>>>(x, cond, cond + CSZ, xa);

  for (int i = 0; i < 3; i++){
    qkvg_gemm<<<dim3(4, MTOT/128), 256, 0, stream>>>(xa,
        wt + WT_QKVG_OFF + (size_t)i*4*16384, bq + (size_t)i*CA, qkvg);
    attn_kernel<<<dim3(NWIN, BB), 256, 0, stream>>>(qkvg,
        biasg + (size_t)i*BIAS_I, amask, go);
    resid_fused<128,true><<<MTOT/128, 256, 0, stream>>>(go,
        wt + WT_WO_OFF + (size_t)i*16384, cond + (size_t)(i*6+2)*CSZ, x,
        cond + (size_t)(i*6+3)*CSZ, cond + (size_t)(i*6+4)*CSZ, xa);
    t12_gemm<<<dim3(2, MTOT/128), 256, 0, stream>>>(xa,
        wt + WT_T12_OFF + (size_t)(2*i)*32768,
        wt + WT_T12_OFF + (size_t)(2*i+1)*32768, hsw);
    if (i < 2)
      resid_fused<256,true><<<MTOT/128, 256, 0, stream>>>(hsw,
          wt + WT_WTO_OFF + (size_t)i*32768, cond + (size_t)(i*6+5)*CSZ, x,
          cond + (size_t)((i+1)*6+0)*CSZ, cond + (size_t)((i+1)*6+1)*CSZ, xa);
    else
      resid_fused<256,false><<<MTOT/128, 256, 0, stream>>>(hsw,
          wt + WT_WTO_OFF + (size_t)i*32768, cond + (size_t)(i*6+5)*CSZ, x,
          nullptr, nullptr, nullptr);
  }
  final_kernel<<<MTOT/4, 256, 0, stream>>>(x, amask, lnq_g, lnq_b, Wout, out);
}